// Round 1
// baseline (630.229 us; speedup 1.0000x reference)
//
#include <hip/hip_runtime.h>
#include <stdint.h>

// Problem constants (B=4, T=2048, C=1024, H=16, HD=64)
#define TSEQ 2048
#define CDIM 1024
#define NHEAD 16
#define HDIM 64
#define NROWS 8192  // B*T

typedef __bf16 bf16x8 __attribute__((ext_vector_type(8)));
typedef float f32x4 __attribute__((ext_vector_type(4)));

__device__ __forceinline__ unsigned short f2bf(float f) {
  unsigned u = __builtin_bit_cast(unsigned, f);
  u = u + 0x7fffu + ((u >> 16) & 1u);
  return (unsigned short)(u >> 16);
}

__device__ __forceinline__ float gelu_f(float x) {
  float x3 = x * x * x;
  float z = 0.7978845608028654f * (x + 0.044715f * x3);
  float e = __expf(2.f * z);
  float t = 1.f - 2.f / (e + 1.f);
  return 0.5f * x * (1.f + t);
}

// async 16B global->LDS (lds dest must be wave-uniform; HW adds lane*16)
__device__ __forceinline__ void ldg_lds16(void* lds, const void* gsrc) {
  __builtin_amdgcn_global_load_lds(
      (__attribute__((address_space(1))) unsigned int*)(uintptr_t)gsrc,
      (__attribute__((address_space(3))) unsigned int*)lds,
      16, 0, 0);
}

// ---------------- weight transpose+convert: W fp32 [K][N] -> Wt bf16 [N][K]
__global__ __launch_bounds__(256) void k_wtrans(const float* __restrict__ W,
                                                unsigned short* __restrict__ Wt,
                                                int K, int N) {
  __shared__ unsigned short tl[32][40];
  int n0 = blockIdx.x * 32, k0 = blockIdx.y * 32;
  int tid = threadIdx.x;
  int r = tid >> 3, c4 = (tid & 7) * 4;
  float4 v = *(const float4*)(W + (size_t)(k0 + r) * N + n0 + c4);
  ushort4 o;
  o.x = f2bf(v.x); o.y = f2bf(v.y); o.z = f2bf(v.z); o.w = f2bf(v.w);
  *(ushort4*)&tl[r][c4] = o;
  __syncthreads();
  int n = tid >> 3, k4 = (tid & 7) * 4;
  ushort4 w;
  w.x = tl[k4 + 0][n]; w.y = tl[k4 + 1][n]; w.z = tl[k4 + 2][n]; w.w = tl[k4 + 3][n];
  *(ushort4*)(Wt + (size_t)(n0 + n) * K + k0 + k4) = w;
}

// ---------------- layernorm: fp32 [rows][1024] -> bf16 [rows][1024]
__global__ __launch_bounds__(256) void k_ln(const float* __restrict__ x,
                                            const float* __restrict__ w,
                                            const float* __restrict__ b,
                                            unsigned short* __restrict__ out) {
  int row = blockIdx.x;
  int tid = threadIdx.x;
  const float* xr = x + (size_t)row * CDIM;
  float4 v = *(const float4*)(xr + tid * 4);
  float s = v.x + v.y + v.z + v.w;
  float s2 = v.x * v.x + v.y * v.y + v.z * v.z + v.w * v.w;
#pragma unroll
  for (int off = 32; off; off >>= 1) {
    s += __shfl_xor(s, off);
    s2 += __shfl_xor(s2, off);
  }
  __shared__ float rbuf[8];
  int wv = tid >> 6, lane = tid & 63;
  if (lane == 0) { rbuf[wv] = s; rbuf[4 + wv] = s2; }
  __syncthreads();
  float S1 = rbuf[0] + rbuf[1] + rbuf[2] + rbuf[3];
  float S2 = rbuf[4] + rbuf[5] + rbuf[6] + rbuf[7];
  float mean = S1 * (1.f / CDIM);
  float var = S2 * (1.f / CDIM) - mean * mean;
  float rstd = rsqrtf(var + 1e-5f);
  float4 wv4 = *(const float4*)(w + tid * 4);
  float4 bv4 = *(const float4*)(b + tid * 4);
  ushort4 o;
  o.x = f2bf((v.x - mean) * rstd * wv4.x + bv4.x);
  o.y = f2bf((v.y - mean) * rstd * wv4.y + bv4.y);
  o.z = f2bf((v.z - mean) * rstd * wv4.z + bv4.z);
  o.w = f2bf((v.w - mean) * rstd * wv4.w + bv4.w);
  *(ushort4*)(out + (size_t)row * CDIM + tid * 4) = o;
}

// ---------------- bf16 GEMM, m97 structure: C[M,N] = A[M,K] @ Bt[N,K]^T (+epilogue)
// EPI 0: +bias -> bf16 out; EPI 1: gelu(+bias) -> bf16 out; EPI 2: +bias+resid -> fp32 out
template <int EPI>
__global__ __launch_bounds__(256)
void k_gemm(const unsigned short* __restrict__ A,
            const unsigned short* __restrict__ Bt,
            const float* __restrict__ bias,
            const float* __restrict__ resid,
            void* __restrict__ Cout,
            int M, int N, int K) {
  __shared__ __align__(16) unsigned short As[128 * 32];
  __shared__ __align__(16) unsigned short Bs[128 * 32];
  const int tid = threadIdx.x;
  const int wv = tid >> 6, lane = tid & 63;
  const int wm = wv >> 1, wn = wv & 1;
  const int fr = lane & 15, fq = lane >> 4;
  const long brow = (long)blockIdx.y * 128, bcol = (long)blockIdx.x * 128;
  const int sub = lane >> 2, cb = (lane & 3) * 8;  // staging row/col within chunk

  const unsigned short* Ag = A + (brow + wv * 32 + sub) * (long)K + cb;
  const unsigned short* Bg = Bt + (bcol + wv * 32 + sub) * (long)K + cb;
  unsigned short* AsB = &As[wv * 1024];  // wave-uniform LDS staging base
  unsigned short* BsB = &Bs[wv * 1024];

  f32x4 acc[4][4];
  const f32x4 vzero = {0.f, 0.f, 0.f, 0.f};
#pragma unroll
  for (int m = 0; m < 4; ++m)
#pragma unroll
    for (int n = 0; n < 4; ++n) acc[m][n] = vzero;

  for (int k0 = 0; k0 < K; k0 += 32) {
    ldg_lds16(AsB, Ag + k0);
    ldg_lds16(AsB + 512, Ag + 16 * (long)K + k0);
    ldg_lds16(BsB, Bg + k0);
    ldg_lds16(BsB + 512, Bg + 16 * (long)K + k0);
    __syncthreads();
    bf16x8 af[4], bfr[4];
#pragma unroll
    for (int m = 0; m < 4; ++m)
      af[m] = *(const bf16x8*)&As[(wm * 64 + m * 16 + fr) * 32 + fq * 8];
#pragma unroll
    for (int n = 0; n < 4; ++n)
      bfr[n] = *(const bf16x8*)&Bs[(wn * 64 + n * 16 + fr) * 32 + fq * 8];
#pragma unroll
    for (int m = 0; m < 4; ++m)
#pragma unroll
      for (int n = 0; n < 4; ++n)
        acc[m][n] = __builtin_amdgcn_mfma_f32_16x16x32_bf16(af[m], bfr[n], acc[m][n], 0, 0, 0);
    __syncthreads();
  }

#pragma unroll
  for (int m = 0; m < 4; ++m) {
    long row = brow + wm * 64 + m * 16 + fq * 4;
#pragma unroll
    for (int n = 0; n < 4; ++n) {
      long col = bcol + wn * 64 + n * 16 + fr;
      float bv = bias[col];
#pragma unroll
      for (int r = 0; r < 4; ++r) {
        float v = acc[m][n][r] + bv;
        long idx = (row + r) * (long)N + col;
        if (EPI == 0) {
          ((unsigned short*)Cout)[idx] = f2bf(v);
        } else if (EPI == 1) {
          ((unsigned short*)Cout)[idx] = f2bf(gelu_f(v));
        } else {
          ((float*)Cout)[idx] = v + resid[idx];
        }
      }
    }
  }
}

// ---------------- build V^T: qkv bf16 [8192][3072] (v at col 2048+h*64) -> vt [b,h,64,2048]
__global__ __launch_bounds__(256) void k_build_vt(const unsigned short* __restrict__ qkv,
                                                  unsigned short* __restrict__ vt) {
  __shared__ __align__(16) unsigned short tl[64][80];
  int bh = blockIdx.x, b = bh >> 4, h = bh & 15;
  int t0 = blockIdx.y * 64;
  int tid = threadIdx.x;
  int r = tid >> 2, cb = (tid & 3) * 16;
  const unsigned short* src =
      qkv + (size_t)(b * TSEQ + t0 + r) * (3 * CDIM) + 2 * CDIM + h * HDIM + cb;
  *(uint4*)&tl[r][cb] = *(const uint4*)src;
  *(uint4*)&tl[r][cb + 8] = *(const uint4*)(src + 8);
  __syncthreads();
  int d = tid >> 2, tb = (tid & 3) * 16;
  union { unsigned short u[16]; uint4 v[2]; } o;
#pragma unroll
  for (int j = 0; j < 16; ++j) o.u[j] = tl[tb + j][d];
  unsigned short* dst = vt + ((size_t)bh * HDIM + d) * TSEQ + t0 + tb;
  *(uint4*)dst = o.v[0];
  *(uint4*)(dst + 8) = o.v[1];
}

// ---------------- flash attention (causal): q,k from qkv bf16, v from vt; out y bf16 [8192][1024]
__global__ __launch_bounds__(256) void k_attn(const unsigned short* __restrict__ qkv,
                                              const unsigned short* __restrict__ vt,
                                              unsigned short* __restrict__ y) {
  __shared__ __align__(16) unsigned short Pl[4][16][32];
  int bh = blockIdx.x, b = bh >> 4, h = bh & 15;
  int wv = threadIdx.x >> 6, lane = threadIdx.x & 63;
  int q0 = blockIdx.y * 64 + wv * 16;  // this wave's 16 q-rows
  int fr = lane & 15, fq = lane >> 4;

  // Q fragments (two K=32 windows over HD=64), hoisted
  const unsigned short* qb = qkv + (size_t)(b * TSEQ + q0 + fr) * (3 * CDIM) + h * HDIM;
  bf16x8 qf0 = *(const bf16x8*)(qb + fq * 8);
  bf16x8 qf1 = *(const bf16x8*)(qb + 32 + fq * 8);

  const f32x4 vzero = {0.f, 0.f, 0.f, 0.f};
  f32x4 O0 = vzero, O1 = vzero, O2 = vzero, O3 = vzero;
  float mrow[4], lrow[4];
#pragma unroll
  for (int r = 0; r < 4; ++r) { mrow[r] = -1e30f; lrow[r] = 0.f; }

  int ntile = (q0 + 15) / 32 + 1;
  for (int t = 0; t < ntile; ++t) {
    int kv0 = t * 32;
    // S = Q K^T for two 16-col halves
    f32x4 S0 = vzero, S1 = vzero;
    {
      const unsigned short* kb0 =
          qkv + (size_t)(b * TSEQ + kv0 + fr) * (3 * CDIM) + CDIM + h * HDIM;
      bf16x8 ka = *(const bf16x8*)(kb0 + fq * 8);
      bf16x8 kbf = *(const bf16x8*)(kb0 + 32 + fq * 8);
      S0 = __builtin_amdgcn_mfma_f32_16x16x32_bf16(qf0, ka, S0, 0, 0, 0);
      S0 = __builtin_amdgcn_mfma_f32_16x16x32_bf16(qf1, kbf, S0, 0, 0, 0);
      const unsigned short* kb1 =
          qkv + (size_t)(b * TSEQ + kv0 + 16 + fr) * (3 * CDIM) + CDIM + h * HDIM;
      bf16x8 kc = *(const bf16x8*)(kb1 + fq * 8);
      bf16x8 kd = *(const bf16x8*)(kb1 + 32 + fq * 8);
      S1 = __builtin_amdgcn_mfma_f32_16x16x32_bf16(qf0, kc, S1, 0, 0, 0);
      S1 = __builtin_amdgcn_mfma_f32_16x16x32_bf16(qf1, kd, S1, 0, 0, 0);
    }
    // online softmax (C/D layout: col=fr, row=fq*4+r)
#pragma unroll
    for (int r = 0; r < 4; ++r) {
      int q = q0 + fq * 4 + r;
      float s0 = S0[r] * 0.125f;
      float s1 = S1[r] * 0.125f;
      if (kv0 + fr > q) s0 = -1e30f;
      if (kv0 + 16 + fr > q) s1 = -1e30f;
      float tm = fmaxf(s0, s1);
      tm = fmaxf(tm, __shfl_xor(tm, 1));
      tm = fmaxf(tm, __shfl_xor(tm, 2));
      tm = fmaxf(tm, __shfl_xor(tm, 4));
      tm = fmaxf(tm, __shfl_xor(tm, 8));
      float mnew = fmaxf(mrow[r], tm);
      float alpha = __expf(mrow[r] - mnew);
      mrow[r] = mnew;
      float p0 = __expf(s0 - mnew);
      float p1 = __expf(s1 - mnew);
      float rs = p0 + p1;
      rs += __shfl_xor(rs, 1);
      rs += __shfl_xor(rs, 2);
      rs += __shfl_xor(rs, 4);
      rs += __shfl_xor(rs, 8);
      lrow[r] = lrow[r] * alpha + rs;
      O0[r] *= alpha; O1[r] *= alpha; O2[r] *= alpha; O3[r] *= alpha;
      Pl[wv][fq * 4 + r][fr] = f2bf(p0);
      Pl[wv][fq * 4 + r][16 + fr] = f2bf(p1);
    }
    // PV: A = P (16x32), B = V^T fragments
    bf16x8 pf = *(const bf16x8*)&Pl[wv][fr][fq * 8];
    const unsigned short* vb = vt + ((size_t)bh * HDIM + fr) * TSEQ + kv0 + fq * 8;
    bf16x8 v0 = *(const bf16x8*)(vb);
    bf16x8 v1 = *(const bf16x8*)(vb + 16 * TSEQ);
    bf16x8 v2 = *(const bf16x8*)(vb + 32 * TSEQ);
    bf16x8 v3 = *(const bf16x8*)(vb + 48 * TSEQ);
    O0 = __builtin_amdgcn_mfma_f32_16x16x32_bf16(pf, v0, O0, 0, 0, 0);
    O1 = __builtin_amdgcn_mfma_f32_16x16x32_bf16(pf, v1, O1, 0, 0, 0);
    O2 = __builtin_amdgcn_mfma_f32_16x16x32_bf16(pf, v2, O2, 0, 0, 0);
    O3 = __builtin_amdgcn_mfma_f32_16x16x32_bf16(pf, v3, O3, 0, 0, 0);
  }
  // finalize: O /= l, store y[b,t,h*64+d]
#pragma unroll
  for (int r = 0; r < 4; ++r) {
    float inv = 1.f / lrow[r];
    int q = q0 + fq * 4 + r;
    unsigned short* yr = y + (size_t)(b * TSEQ + q) * CDIM + h * HDIM + fr;
    yr[0] = f2bf(O0[r] * inv);
    yr[16] = f2bf(O1[r] * inv);
    yr[32] = f2bf(O2[r] * inv);
    yr[48] = f2bf(O3[r] * inv);
  }
}

// ---------------- launch
extern "C" void kernel_launch(void* const* d_in, const int* in_sizes, int n_in,
                              void* d_out, int out_size, void* d_ws, size_t ws_size,
                              hipStream_t stream) {
  const float* x = (const float*)d_in[0];
  const float* ln1_w = (const float*)d_in[1];
  const float* ln1_b = (const float*)d_in[2];
  const float* attn_w = (const float*)d_in[3];
  const float* attn_b = (const float*)d_in[4];
  const float* proj_w = (const float*)d_in[5];
  const float* proj_b = (const float*)d_in[6];
  const float* ln2_w = (const float*)d_in[7];
  const float* ln2_b = (const float*)d_in[8];
  const float* fc_w = (const float*)d_in[9];
  const float* fc_b = (const float*)d_in[10];
  const float* fc_proj_w = (const float*)d_in[11];
  const float* fc_proj_b = (const float*)d_in[12];

  char* ws = (char*)d_ws;
  // workspace layout (bytes)
  unsigned short* wt_attn = (unsigned short*)(ws + 0);           // [3072][1024] bf16, 6.29MB
  unsigned short* wt_proj = (unsigned short*)(ws + 6291456);     // [1024][1024]
  unsigned short* wt_fc = (unsigned short*)(ws + 8388608);       // [4096][1024]
  unsigned short* wt_fcp = (unsigned short*)(ws + 16777216);     // [1024][4096]
  float* x1 = (float*)(ws + 25165824);                           // [8192][1024] fp32
  unsigned short* hbuf = (unsigned short*)(ws + 58720256);       // [8192][1024] bf16 (ln1 out, reused for ln2 out)
  unsigned short* ybuf = (unsigned short*)(ws + 75497472);       // [8192][1024] bf16
  unsigned short* qkvb = (unsigned short*)(ws + 92274688);       // [8192][3072] bf16
  unsigned short* vtb = (unsigned short*)(ws + 142606336);       // [64][64][2048] bf16
  unsigned short* gbuf = (unsigned short*)(ws + 92274688);       // [8192][4096] bf16, aliases qkv+vt (dead by then)

  // 1. weight transposes (fp32 [K][N] -> bf16 [N][K])
  k_wtrans<<<dim3(3072 / 32, 1024 / 32), 256, 0, stream>>>(attn_w, wt_attn, 1024, 3072);
  k_wtrans<<<dim3(1024 / 32, 1024 / 32), 256, 0, stream>>>(proj_w, wt_proj, 1024, 1024);
  k_wtrans<<<dim3(4096 / 32, 1024 / 32), 256, 0, stream>>>(fc_w, wt_fc, 1024, 4096);
  k_wtrans<<<dim3(1024 / 32, 4096 / 32), 256, 0, stream>>>(fc_proj_w, wt_fcp, 4096, 1024);

  // 2. LN1: x -> hbuf (bf16)
  k_ln<<<NROWS, 256, 0, stream>>>(x, ln1_w, ln1_b, hbuf);

  // 3. qkv = h @ attn_w + attn_b -> bf16
  k_gemm<0><<<dim3(3072 / 128, NROWS / 128), 256, 0, stream>>>(
      hbuf, wt_attn, attn_b, nullptr, qkvb, NROWS, 3072, 1024);

  // 4. V^T
  k_build_vt<<<dim3(64, TSEQ / 64), 256, 0, stream>>>(qkvb, vtb);

  // 5. flash attention -> ybuf
  k_attn<<<dim3(64, TSEQ / 64), 256, 0, stream>>>(qkvb, vtb, ybuf);

  // 6. x1 = x + y @ proj_w + proj_b (fp32)
  k_gemm<2><<<dim3(1024 / 128, NROWS / 128), 256, 0, stream>>>(
      ybuf, wt_proj, proj_b, x, x1, NROWS, 1024, 1024);

  // 7. LN2: x1 -> hbuf (bf16)
  k_ln<<<NROWS, 256, 0, stream>>>(x1, ln2_w, ln2_b, hbuf);

  // 8. g = gelu(h @ fc_w + fc_b) -> bf16
  k_gemm<1><<<dim3(4096 / 128, NROWS / 128), 256, 0, stream>>>(
      hbuf, wt_fc, fc_b, nullptr, gbuf, NROWS, 4096, 1024);

  // 9. out = x1 + g @ fc_proj_w + fc_proj_b (fp32)
  k_gemm<2><<<dim3(1024 / 128, NROWS / 128), 256, 0, stream>>>(
      gbuf, wt_fcp, fc_proj_b, x1, (float*)d_out, NROWS, 1024, 4096);
}

// Round 2
// 519.782 us; speedup vs baseline: 1.2125x; 1.2125x over previous
//
#include <hip/hip_runtime.h>
#include <stdint.h>

// Problem constants (B=4, T=2048, C=1024, H=16, HD=64)
#define TSEQ 2048
#define CDIM 1024
#define NHEAD 16
#define HDIM 64
#define NROWS 8192  // B*T

typedef __bf16 bf16x8 __attribute__((ext_vector_type(8)));
typedef float f32x4 __attribute__((ext_vector_type(4)));
typedef float f32x16 __attribute__((ext_vector_type(16)));

__device__ __forceinline__ unsigned short f2bf(float f) {
  unsigned u = __builtin_bit_cast(unsigned, f);
  u = u + 0x7fffu + ((u >> 16) & 1u);
  return (unsigned short)(u >> 16);
}

__device__ __forceinline__ unsigned cvt_pk_bf16(float a, float b) {
  unsigned r;
  asm("v_cvt_pk_bf16_f32 %0, %1, %2" : "=v"(r) : "v"(a), "v"(b));
  return r;
}

__device__ __forceinline__ float gelu_f(float x) {
  float x3 = x * x * x;
  float z = 0.7978845608028654f * (x + 0.044715f * x3);
  float e = __expf(2.f * z);
  float t = 1.f - 2.f / (e + 1.f);
  return 0.5f * x * (1.f + t);
}

// async 16B global->LDS (lds dest must be wave-uniform; HW adds lane*16)
__device__ __forceinline__ void ldg_lds16(void* lds, const void* gsrc) {
  __builtin_amdgcn_global_load_lds(
      (__attribute__((address_space(1))) unsigned int*)(uintptr_t)gsrc,
      (__attribute__((address_space(3))) unsigned int*)lds,
      16, 0, 0);
}

// ---------------- weight transpose+convert: W fp32 [K][N] -> Wt bf16 [N][K]
__global__ __launch_bounds__(256) void k_wtrans(const float* __restrict__ W,
                                                unsigned short* __restrict__ Wt,
                                                int K, int N) {
  __shared__ unsigned short tl[32][40];
  int n0 = blockIdx.x * 32, k0 = blockIdx.y * 32;
  int tid = threadIdx.x;
  int r = tid >> 3, c4 = (tid & 7) * 4;
  float4 v = *(const float4*)(W + (size_t)(k0 + r) * N + n0 + c4);
  ushort4 o;
  o.x = f2bf(v.x); o.y = f2bf(v.y); o.z = f2bf(v.z); o.w = f2bf(v.w);
  *(ushort4*)&tl[r][c4] = o;
  __syncthreads();
  int n = tid >> 3, k4 = (tid & 7) * 4;
  ushort4 w;
  w.x = tl[k4 + 0][n]; w.y = tl[k4 + 1][n]; w.z = tl[k4 + 2][n]; w.w = tl[k4 + 3][n];
  *(ushort4*)(Wt + (size_t)(n0 + n) * K + k0 + k4) = w;
}

// ---------------- layernorm: fp32 [rows][1024] -> bf16 [rows][1024]
__global__ __launch_bounds__(256) void k_ln(const float* __restrict__ x,
                                            const float* __restrict__ w,
                                            const float* __restrict__ b,
                                            unsigned short* __restrict__ out) {
  int row = blockIdx.x;
  int tid = threadIdx.x;
  const float* xr = x + (size_t)row * CDIM;
  float4 v = *(const float4*)(xr + tid * 4);
  float s = v.x + v.y + v.z + v.w;
  float s2 = v.x * v.x + v.y * v.y + v.z * v.z + v.w * v.w;
#pragma unroll
  for (int off = 32; off; off >>= 1) {
    s += __shfl_xor(s, off);
    s2 += __shfl_xor(s2, off);
  }
  __shared__ float rbuf[8];
  int wv = tid >> 6, lane = tid & 63;
  if (lane == 0) { rbuf[wv] = s; rbuf[4 + wv] = s2; }
  __syncthreads();
  float S1 = rbuf[0] + rbuf[1] + rbuf[2] + rbuf[3];
  float S2 = rbuf[4] + rbuf[5] + rbuf[6] + rbuf[7];
  float mean = S1 * (1.f / CDIM);
  float var = S2 * (1.f / CDIM) - mean * mean;
  float rstd = rsqrtf(var + 1e-5f);
  float4 wv4 = *(const float4*)(w + tid * 4);
  float4 bv4 = *(const float4*)(b + tid * 4);
  ushort4 o;
  o.x = f2bf((v.x - mean) * rstd * wv4.x + bv4.x);
  o.y = f2bf((v.y - mean) * rstd * wv4.y + bv4.y);
  o.z = f2bf((v.z - mean) * rstd * wv4.z + bv4.z);
  o.w = f2bf((v.w - mean) * rstd * wv4.w + bv4.w);
  *(ushort4*)(out + (size_t)row * CDIM + tid * 4) = o;
}

// ---------------- bf16 GEMM, m97 structure: C[M,N] = A[M,K] @ Bt[N,K]^T (+epilogue)
// EPI 0: +bias -> bf16 out; EPI 1: gelu(+bias) -> bf16 out; EPI 2: +bias+resid -> fp32 out
template <int EPI>
__global__ __launch_bounds__(256)
void k_gemm(const unsigned short* __restrict__ A,
            const unsigned short* __restrict__ Bt,
            const float* __restrict__ bias,
            const float* __restrict__ resid,
            void* __restrict__ Cout,
            int M, int N, int K) {
  __shared__ __align__(16) unsigned short As[128 * 32];
  __shared__ __align__(16) unsigned short Bs[128 * 32];
  const int tid = threadIdx.x;
  const int wv = tid >> 6, lane = tid & 63;
  const int wm = wv >> 1, wn = wv & 1;
  const int fr = lane & 15, fq = lane >> 4;
  const long brow = (long)blockIdx.y * 128, bcol = (long)blockIdx.x * 128;
  const int sub = lane >> 2, cb = (lane & 3) * 8;  // staging row/col within chunk

  const unsigned short* Ag = A + (brow + wv * 32 + sub) * (long)K + cb;
  const unsigned short* Bg = Bt + (bcol + wv * 32 + sub) * (long)K + cb;
  unsigned short* AsB = &As[wv * 1024];  // wave-uniform LDS staging base
  unsigned short* BsB = &Bs[wv * 1024];

  f32x4 acc[4][4];
  const f32x4 vzero = {0.f, 0.f, 0.f, 0.f};
#pragma unroll
  for (int m = 0; m < 4; ++m)
#pragma unroll
    for (int n = 0; n < 4; ++n) acc[m][n] = vzero;

  for (int k0 = 0; k0 < K; k0 += 32) {
    ldg_lds16(AsB, Ag + k0);
    ldg_lds16(AsB + 512, Ag + 16 * (long)K + k0);
    ldg_lds16(BsB, Bg + k0);
    ldg_lds16(BsB + 512, Bg + 16 * (long)K + k0);
    __syncthreads();
    bf16x8 af[4], bfr[4];
#pragma unroll
    for (int m = 0; m < 4; ++m)
      af[m] = *(const bf16x8*)&As[(wm * 64 + m * 16 + fr) * 32 + fq * 8];
#pragma unroll
    for (int n = 0; n < 4; ++n)
      bfr[n] = *(const bf16x8*)&Bs[(wn * 64 + n * 16 + fr) * 32 + fq * 8];
#pragma unroll
    for (int m = 0; m < 4; ++m)
#pragma unroll
      for (int n = 0; n < 4; ++n)
        acc[m][n] = __builtin_amdgcn_mfma_f32_16x16x32_bf16(af[m], bfr[n], acc[m][n], 0, 0, 0);
    __syncthreads();
  }

#pragma unroll
  for (int m = 0; m < 4; ++m) {
    long row = brow + wm * 64 + m * 16 + fq * 4;
#pragma unroll
    for (int n = 0; n < 4; ++n) {
      long col = bcol + wn * 64 + n * 16 + fr;
      float bv = bias[col];
#pragma unroll
      for (int r = 0; r < 4; ++r) {
        float v = acc[m][n][r] + bv;
        long idx = (row + r) * (long)N + col;
        if (EPI == 0) {
          ((unsigned short*)Cout)[idx] = f2bf(v);
        } else if (EPI == 1) {
          ((unsigned short*)Cout)[idx] = f2bf(gelu_f(v));
        } else {
          ((float*)Cout)[idx] = v + resid[idx];
        }
      }
    }
  }
}

// ---------------- build V^T: qkv bf16 [8192][3072] (v at col 2048+h*64) -> vt [b,h,64,2048]
__global__ __launch_bounds__(256) void k_build_vt(const unsigned short* __restrict__ qkv,
                                                  unsigned short* __restrict__ vt) {
  __shared__ __align__(16) unsigned short tl[64][80];
  int bh = blockIdx.x, b = bh >> 4, h = bh & 15;
  int t0 = blockIdx.y * 64;
  int tid = threadIdx.x;
  int r = tid >> 2, cb = (tid & 3) * 16;
  const unsigned short* src =
      qkv + (size_t)(b * TSEQ + t0 + r) * (3 * CDIM) + 2 * CDIM + h * HDIM + cb;
  *(uint4*)&tl[r][cb] = *(const uint4*)src;
  *(uint4*)&tl[r][cb + 8] = *(const uint4*)(src + 8);
  __syncthreads();
  int d = tid >> 2, tb = (tid & 3) * 16;
  union { unsigned short u[16]; uint4 v[2]; } o;
#pragma unroll
  for (int j = 0; j < 16; ++j) o.u[j] = tl[tb + j][d];
  unsigned short* dst = vt + ((size_t)bh * HDIM + d) * TSEQ + t0 + tb;
  *(uint4*)dst = o.v[0];
  *(uint4*)(dst + 8) = o.v[1];
}

// ---------------- flash attention (causal), swapped-QK^T 32x32 structure.
// Per wave: 32 q rows. mfma(K,Q) -> S^T: lane owns q-col (lane&31), 16 kv regs;
// softmax lane-local (1 shfl for cross-half reduce); P packed to bf16 in-reg,
// 8 shfl_xor(32) rebuild PV B-frag. No LDS, no barriers.
__global__ __launch_bounds__(256) void k_attn(const unsigned short* __restrict__ qkv,
                                              const unsigned short* __restrict__ vt,
                                              unsigned short* __restrict__ y) {
  const int bh = blockIdx.x, b = bh >> 4, h = bh & 15;
  const int wv = threadIdx.x >> 6, lane = threadIdx.x & 63;
  const int q0 = (gridDim.y - 1 - blockIdx.y) * 128 + wv * 32;  // heavy blocks first
  const int lq = lane & 31, hi = lane >> 5;
  const int q = q0 + lq;

  // Q fragments (B-operand of 32x32x16): B[k][j=q]; lane j=lq reads Q row q, k=ki*16+hi*8+e
  const unsigned short* qrow = qkv + ((size_t)(b * TSEQ) + q) * (3 * CDIM) + h * HDIM;
  bf16x8 qf[4];
#pragma unroll
  for (int ki = 0; ki < 4; ++ki) qf[ki] = *(const bf16x8*)(qrow + ki * 16 + hi * 8);

  const unsigned short* vbase = vt + ((size_t)bh * HDIM + lq) * TSEQ;  // V^T row d=lq
  const unsigned short* kbase = qkv + ((size_t)(b * TSEQ) + lq) * (3 * CDIM) + CDIM + h * HDIM;

  f32x16 OTlo, OThi;
#pragma unroll
  for (int r = 0; r < 16; ++r) { OTlo[r] = 0.f; OThi[r] = 0.f; }
  float m = -1e30f, l = 0.f;
  const float SC = 0.125f * 1.44269504088896f;  // 1/sqrt(HD) * log2(e): exp2 domain

  const int nt = q0 >> 5;  // diagonal tile index
  for (int t = 0; t <= nt; ++t) {
    const int kv0 = t << 5;
    // K fragments (A-operand): A[i=kv][k]; lane i=lq reads K row kv0+lq
    const unsigned short* krow = kbase + (size_t)kv0 * (3 * CDIM);
    bf16x8 kf[4];
#pragma unroll
    for (int ki = 0; ki < 4; ++ki) kf[ki] = *(const bf16x8*)(krow + ki * 16 + hi * 8);
    f32x16 st;
#pragma unroll
    for (int r = 0; r < 16; ++r) st[r] = 0.f;
#pragma unroll
    for (int ki = 0; ki < 4; ++ki)
      st = __builtin_amdgcn_mfma_f32_32x32x16_bf16(kf[ki], qf[ki], st, 0, 0, 0);
    // S^T[kv_local][q]: kv_local(r,hi) = (r&3) + 8*(r>>2) + 4*hi, col q = lq
    float s[16];
#pragma unroll
    for (int r = 0; r < 16; ++r) s[r] = st[r] * SC;
    if (t == nt) {  // diagonal tile: mask kv > q  (kv0 == q0 here)
#pragma unroll
      for (int r = 0; r < 16; ++r) {
        int kvl = (r & 3) + 8 * (r >> 2) + 4 * hi;
        if (kvl > lq) s[r] = -1e30f;
      }
    }
    float tmax = s[0];
#pragma unroll
    for (int r = 1; r < 16; ++r) tmax = fmaxf(tmax, s[r]);
    float tm = fmaxf(tmax, __shfl_xor(tmax, 32));
    if (__any(tm > m + 8.f)) {  // T13 defer-max: skip rescale unless max grew >8 (log2)
      float mnew = fmaxf(m, tm);
      float alpha = __builtin_amdgcn_exp2f(m - mnew);
      m = mnew;
      OTlo *= alpha;
      OThi *= alpha;
      l *= alpha;
    }
    float p[16];
    float rs = 0.f;
#pragma unroll
    for (int r = 0; r < 16; ++r) {
      p[r] = __builtin_amdgcn_exp2f(s[r] - m);
      rs += p[r];
    }
    l += rs + __shfl_xor(rs, 32);
    // pack P to bf16 pairs: c[i] = (p[2i+1]<<16)|p[2i]; kv pairs (2i,2i+1) of this half
    unsigned c[8];
#pragma unroll
    for (int i = 0; i < 8; ++i) c[i] = cvt_pk_bf16(p[2 * i], p[2 * i + 1]);
    unsigned pc[8];
#pragma unroll
    for (int i = 0; i < 8; ++i) pc[i] = __shfl_xor(c[i], 32);
    // B-frag words: kv = khalf*16 + hi*8 + {0..7}
    uint4 w1, w2;
    w1.x = hi ? pc[2] : c[0]; w1.y = hi ? pc[3] : c[1];
    w1.z = hi ? c[2] : pc[0]; w1.w = hi ? c[3] : pc[1];
    w2.x = hi ? pc[6] : c[4]; w2.y = hi ? pc[7] : c[5];
    w2.z = hi ? c[6] : pc[4]; w2.w = hi ? c[7] : pc[5];
    bf16x8 f1 = __builtin_bit_cast(bf16x8, w1);
    bf16x8 f2 = __builtin_bit_cast(bf16x8, w2);
    // PV: OT[d][q] += V^T[d][kv] * P^T[kv][q]
    const unsigned short* vrow = vbase + kv0;
    bf16x8 va0 = *(const bf16x8*)(vrow + hi * 8);
    bf16x8 va1 = *(const bf16x8*)(vrow + 16 + hi * 8);
    bf16x8 vb0 = *(const bf16x8*)(vrow + 32 * TSEQ + hi * 8);
    bf16x8 vb1 = *(const bf16x8*)(vrow + 32 * TSEQ + 16 + hi * 8);
    OTlo = __builtin_amdgcn_mfma_f32_32x32x16_bf16(va0, f1, OTlo, 0, 0, 0);
    OTlo = __builtin_amdgcn_mfma_f32_32x32x16_bf16(va1, f2, OTlo, 0, 0, 0);
    OThi = __builtin_amdgcn_mfma_f32_32x32x16_bf16(vb0, f1, OThi, 0, 0, 0);
    OThi = __builtin_amdgcn_mfma_f32_32x32x16_bf16(vb1, f2, OThi, 0, 0, 0);
  }
  // finalize: O^T col q = lq, rows d per acc layout; store y[b,q,h*64+d]
  float inv = 1.f / l;
  unsigned short* yrow = y + ((size_t)(b * TSEQ) + q) * CDIM + h * HDIM;
#pragma unroll
  for (int r = 0; r < 16; r += 2) {
    int d = (r & 3) + 8 * (r >> 2) + 4 * hi;
    unsigned lo0 = f2bf(OTlo[r] * inv), lo1 = f2bf(OTlo[r + 1] * inv);
    *(unsigned*)(yrow + d) = lo0 | (lo1 << 16);
    unsigned h0 = f2bf(OThi[r] * inv), h1 = f2bf(OThi[r + 1] * inv);
    *(unsigned*)(yrow + 32 + d) = h0 | (h1 << 16);
  }
}

// ---------------- launch
extern "C" void kernel_launch(void* const* d_in, const int* in_sizes, int n_in,
                              void* d_out, int out_size, void* d_ws, size_t ws_size,
                              hipStream_t stream) {
  const float* x = (const float*)d_in[0];
  const float* ln1_w = (const float*)d_in[1];
  const float* ln1_b = (const float*)d_in[2];
  const float* attn_w = (const float*)d_in[3];
  const float* attn_b = (const float*)d_in[4];
  const float* proj_w = (const float*)d_in[5];
  const float* proj_b = (const float*)d_in[6];
  const float* ln2_w = (const float*)d_in[7];
  const float* ln2_b = (const float*)d_in[8];
  const float* fc_w = (const float*)d_in[9];
  const float* fc_b = (const float*)d_in[10];
  const float* fc_proj_w = (const float*)d_in[11];
  const float* fc_proj_b = (const float*)d_in[12];

  char* ws = (char*)d_ws;
  // workspace layout (bytes)
  unsigned short* wt_attn = (unsigned short*)(ws + 0);           // [3072][1024] bf16, 6.29MB
  unsigned short* wt_proj = (unsigned short*)(ws + 6291456);     // [1024][1024]
  unsigned short* wt_fc = (unsigned short*)(ws + 8388608);       // [4096][1024]
  unsigned short* wt_fcp = (unsigned short*)(ws + 16777216);     // [1024][4096]
  float* x1 = (float*)(ws + 25165824);                           // [8192][1024] fp32
  unsigned short* hbuf = (unsigned short*)(ws + 58720256);       // [8192][1024] bf16 (ln1 out, reused for ln2 out)
  unsigned short* ybuf = (unsigned short*)(ws + 75497472);       // [8192][1024] bf16
  unsigned short* qkvb = (unsigned short*)(ws + 92274688);       // [8192][3072] bf16
  unsigned short* vtb = (unsigned short*)(ws + 142606336);       // [64][64][2048] bf16
  unsigned short* gbuf = (unsigned short*)(ws + 92274688);       // [8192][4096] bf16, aliases qkv+vt (dead by then)

  // 1. weight transposes (fp32 [K][N] -> bf16 [N][K])
  k_wtrans<<<dim3(3072 / 32, 1024 / 32), 256, 0, stream>>>(attn_w, wt_attn, 1024, 3072);
  k_wtrans<<<dim3(1024 / 32, 1024 / 32), 256, 0, stream>>>(proj_w, wt_proj, 1024, 1024);
  k_wtrans<<<dim3(4096 / 32, 1024 / 32), 256, 0, stream>>>(fc_w, wt_fc, 1024, 4096);
  k_wtrans<<<dim3(1024 / 32, 4096 / 32), 256, 0, stream>>>(fc_proj_w, wt_fcp, 4096, 1024);

  // 2. LN1: x -> hbuf (bf16)
  k_ln<<<NROWS, 256, 0, stream>>>(x, ln1_w, ln1_b, hbuf);

  // 3. qkv = h @ attn_w + attn_b -> bf16
  k_gemm<0><<<dim3(3072 / 128, NROWS / 128), 256, 0, stream>>>(
      hbuf, wt_attn, attn_b, nullptr, qkvb, NROWS, 3072, 1024);

  // 4. V^T
  k_build_vt<<<dim3(64, TSEQ / 64), 256, 0, stream>>>(qkvb, vtb);

  // 5. flash attention -> ybuf
  k_attn<<<dim3(64, TSEQ / 128), 256, 0, stream>>>(qkvb, vtb, ybuf);

  // 6. x1 = x + y @ proj_w + proj_b (fp32)
  k_gemm<2><<<dim3(1024 / 128, NROWS / 128), 256, 0, stream>>>(
      ybuf, wt_proj, proj_b, x, x1, NROWS, 1024, 1024);

  // 7. LN2: x1 -> hbuf (bf16)
  k_ln<<<NROWS, 256, 0, stream>>>(x1, ln2_w, ln2_b, hbuf);

  // 8. g = gelu(h @ fc_w + fc_b) -> bf16
  k_gemm<1><<<dim3(4096 / 128, NROWS / 128), 256, 0, stream>>>(
      hbuf, wt_fc, fc_b, nullptr, gbuf, NROWS, 4096, 1024);

  // 9. out = x1 + g @ fc_proj_w + fc_proj_b (fp32)
  k_gemm<2><<<dim3(1024 / 128, NROWS / 128), 256, 0, stream>>>(
      gbuf, wt_fcp, fc_proj_b, x1, (float*)d_out, NROWS, 1024, 4096);
}

// Round 3
// 480.754 us; speedup vs baseline: 1.3109x; 1.0812x over previous
//
#include <hip/hip_runtime.h>
#include <stdint.h>

// Problem constants (B=4, T=2048, C=1024, H=16, HD=64)
#define TSEQ 2048
#define CDIM 1024
#define NHEAD 16
#define HDIM 64
#define NROWS 8192  // B*T

typedef __bf16 bf16x8 __attribute__((ext_vector_type(8)));
typedef float f32x4 __attribute__((ext_vector_type(4)));
typedef float f32x16 __attribute__((ext_vector_type(16)));

__device__ __forceinline__ unsigned short f2bf(float f) {
  unsigned u = __builtin_bit_cast(unsigned, f);
  u = u + 0x7fffu + ((u >> 16) & 1u);
  return (unsigned short)(u >> 16);
}

__device__ __forceinline__ unsigned cvt_pk_bf16(float a, float b) {
  unsigned r;
  asm("v_cvt_pk_bf16_f32 %0, %1, %2" : "=v"(r) : "v"(a), "v"(b));
  return r;
}

__device__ __forceinline__ float gelu_f(float x) {
  float x3 = x * x * x;
  float z = 0.7978845608028654f * (x + 0.044715f * x3);
  float e = __expf(2.f * z);
  float t = 1.f - 2.f / (e + 1.f);
  return 0.5f * x * (1.f + t);
}

// async 16B global->LDS (lds dest must be wave-uniform; HW adds lane*16)
__device__ __forceinline__ void ldg_lds16(void* lds, const void* gsrc) {
  __builtin_amdgcn_global_load_lds(
      (__attribute__((address_space(1))) unsigned int*)(uintptr_t)gsrc,
      (__attribute__((address_space(3))) unsigned int*)lds,
      16, 0, 0);
}

// ---------------- weight transpose+convert: W fp32 [K][N] -> Wt bf16 [N][K]
__global__ __launch_bounds__(256) void k_wtrans(const float* __restrict__ W,
                                                unsigned short* __restrict__ Wt,
                                                int K, int N) {
  __shared__ unsigned short tl[32][40];
  int n0 = blockIdx.x * 32, k0 = blockIdx.y * 32;
  int tid = threadIdx.x;
  int r = tid >> 3, c4 = (tid & 7) * 4;
  float4 v = *(const float4*)(W + (size_t)(k0 + r) * N + n0 + c4);
  ushort4 o;
  o.x = f2bf(v.x); o.y = f2bf(v.y); o.z = f2bf(v.z); o.w = f2bf(v.w);
  *(ushort4*)&tl[r][c4] = o;
  __syncthreads();
  int n = tid >> 3, k4 = (tid & 7) * 4;
  ushort4 w;
  w.x = tl[k4 + 0][n]; w.y = tl[k4 + 1][n]; w.z = tl[k4 + 2][n]; w.w = tl[k4 + 3][n];
  *(ushort4*)(Wt + (size_t)(n0 + n) * K + k0 + k4) = w;
}

// ---------------- layernorm: fp32 [rows][1024] -> bf16 [rows][1024]
__global__ __launch_bounds__(256) void k_ln(const float* __restrict__ x,
                                            const float* __restrict__ w,
                                            const float* __restrict__ b,
                                            unsigned short* __restrict__ out) {
  int row = blockIdx.x;
  int tid = threadIdx.x;
  const float* xr = x + (size_t)row * CDIM;
  float4 v = *(const float4*)(xr + tid * 4);
  float s = v.x + v.y + v.z + v.w;
  float s2 = v.x * v.x + v.y * v.y + v.z * v.z + v.w * v.w;
#pragma unroll
  for (int off = 32; off; off >>= 1) {
    s += __shfl_xor(s, off);
    s2 += __shfl_xor(s2, off);
  }
  __shared__ float rbuf[8];
  int wv = tid >> 6, lane = tid & 63;
  if (lane == 0) { rbuf[wv] = s; rbuf[4 + wv] = s2; }
  __syncthreads();
  float S1 = rbuf[0] + rbuf[1] + rbuf[2] + rbuf[3];
  float S2 = rbuf[4] + rbuf[5] + rbuf[6] + rbuf[7];
  float mean = S1 * (1.f / CDIM);
  float var = S2 * (1.f / CDIM) - mean * mean;
  float rstd = rsqrtf(var + 1e-5f);
  float4 wv4 = *(const float4*)(w + tid * 4);
  float4 bv4 = *(const float4*)(b + tid * 4);
  ushort4 o;
  o.x = f2bf((v.x - mean) * rstd * wv4.x + bv4.x);
  o.y = f2bf((v.y - mean) * rstd * wv4.y + bv4.y);
  o.z = f2bf((v.z - mean) * rstd * wv4.z + bv4.z);
  o.w = f2bf((v.w - mean) * rstd * wv4.w + bv4.w);
  *(ushort4*)(out + (size_t)row * CDIM + tid * 4) = o;
}

// ---------------- bf16 GEMM, m97 structure: C[M,N] = A[M,K] @ Bt[N,K]^T (+epilogue)
// EPI 0: +bias -> bf16 out; EPI 1: gelu(+bias) -> bf16 out; EPI 2: +bias+resid -> fp32 out
template <int EPI>
__global__ __launch_bounds__(256)
void k_gemm(const unsigned short* __restrict__ A,
            const unsigned short* __restrict__ Bt,
            const float* __restrict__ bias,
            const float* __restrict__ resid,
            void* __restrict__ Cout,
            int M, int N, int K) {
  __shared__ __align__(16) unsigned short As[128 * 32];
  __shared__ __align__(16) unsigned short Bs[128 * 32];
  const int tid = threadIdx.x;
  const int wv = tid >> 6, lane = tid & 63;
  const int wm = wv >> 1, wn = wv & 1;
  const int fr = lane & 15, fq = lane >> 4;
  const long brow = (long)blockIdx.y * 128, bcol = (long)blockIdx.x * 128;
  const int sub = lane >> 2, cb = (lane & 3) * 8;  // staging row/col within chunk

  const unsigned short* Ag = A + (brow + wv * 32 + sub) * (long)K + cb;
  const unsigned short* Bg = Bt + (bcol + wv * 32 + sub) * (long)K + cb;
  unsigned short* AsB = &As[wv * 1024];  // wave-uniform LDS staging base
  unsigned short* BsB = &Bs[wv * 1024];

  f32x4 acc[4][4];
  const f32x4 vzero = {0.f, 0.f, 0.f, 0.f};
#pragma unroll
  for (int m = 0; m < 4; ++m)
#pragma unroll
    for (int n = 0; n < 4; ++n) acc[m][n] = vzero;

  for (int k0 = 0; k0 < K; k0 += 32) {
    ldg_lds16(AsB, Ag + k0);
    ldg_lds16(AsB + 512, Ag + 16 * (long)K + k0);
    ldg_lds16(BsB, Bg + k0);
    ldg_lds16(BsB + 512, Bg + 16 * (long)K + k0);
    __syncthreads();
    bf16x8 af[4], bfr[4];
#pragma unroll
    for (int m = 0; m < 4; ++m)
      af[m] = *(const bf16x8*)&As[(wm * 64 + m * 16 + fr) * 32 + fq * 8];
#pragma unroll
    for (int n = 0; n < 4; ++n)
      bfr[n] = *(const bf16x8*)&Bs[(wn * 64 + n * 16 + fr) * 32 + fq * 8];
#pragma unroll
    for (int m = 0; m < 4; ++m)
#pragma unroll
      for (int n = 0; n < 4; ++n)
        acc[m][n] = __builtin_amdgcn_mfma_f32_16x16x32_bf16(af[m], bfr[n], acc[m][n], 0, 0, 0);
    __syncthreads();
  }

#pragma unroll
  for (int m = 0; m < 4; ++m) {
    long row = brow + wm * 64 + m * 16 + fq * 4;
#pragma unroll
    for (int n = 0; n < 4; ++n) {
      long col = bcol + wn * 64 + n * 16 + fr;
      float bv = bias[col];
#pragma unroll
      for (int r = 0; r < 4; ++r) {
        float v = acc[m][n][r] + bv;
        long idx = (row + r) * (long)N + col;
        if (EPI == 0) {
          ((unsigned short*)Cout)[idx] = f2bf(v);
        } else if (EPI == 1) {
          ((unsigned short*)Cout)[idx] = f2bf(gelu_f(v));
        } else {
          ((float*)Cout)[idx] = v + resid[idx];
        }
      }
    }
  }
}

// ---------------- build V^T: qkv bf16 [8192][3072] (v at col 2048+h*64) -> vt [b,h,64,2048]
__global__ __launch_bounds__(256) void k_build_vt(const unsigned short* __restrict__ qkv,
                                                  unsigned short* __restrict__ vt) {
  __shared__ __align__(16) unsigned short tl[64][80];
  int bh = blockIdx.x, b = bh >> 4, h = bh & 15;
  int t0 = blockIdx.y * 64;
  int tid = threadIdx.x;
  int r = tid >> 2, cb = (tid & 3) * 16;
  const unsigned short* src =
      qkv + (size_t)(b * TSEQ + t0 + r) * (3 * CDIM) + 2 * CDIM + h * HDIM + cb;
  *(uint4*)&tl[r][cb] = *(const uint4*)src;
  *(uint4*)&tl[r][cb + 8] = *(const uint4*)(src + 8);
  __syncthreads();
  int d = tid >> 2, tb = (tid & 3) * 16;
  union { unsigned short u[16]; uint4 v[2]; } o;
#pragma unroll
  for (int j = 0; j < 16; ++j) o.u[j] = tl[tb + j][d];
  unsigned short* dst = vt + ((size_t)bh * HDIM + d) * TSEQ + t0 + tb;
  *(uint4*)dst = o.v[0];
  *(uint4*)(dst + 8) = o.v[1];
}

// ---------------- flash attention (causal), swapped-QK^T 32x32, paired q-tiles.
// Wave w handles q-tiles jlo=w and jhi=63-w -> every wave does exactly 65 tile-steps.
// K/V fragments for tile t are shared by both q-sets; double-buffered reg prefetch.
struct QSt {
  f32x16 OTlo, OThi;
  float m, l;
};

__device__ __forceinline__ void attn_qk_sm_pv(
    const bf16x8& k0, const bf16x8& k1, const bf16x8& k2, const bf16x8& k3,
    const bf16x8& v0, const bf16x8& v1, const bf16x8& v2, const bf16x8& v3,
    const bf16x8& q0f, const bf16x8& q1f, const bf16x8& q2f, const bf16x8& q3f,
    QSt& S, bool diag, int lq, int hi) {
  const float SC = 0.125f * 1.44269504088896f;  // 1/sqrt(HD) * log2(e)
  f32x16 st;
#pragma unroll
  for (int r = 0; r < 16; ++r) st[r] = 0.f;
  st = __builtin_amdgcn_mfma_f32_32x32x16_bf16(k0, q0f, st, 0, 0, 0);
  st = __builtin_amdgcn_mfma_f32_32x32x16_bf16(k1, q1f, st, 0, 0, 0);
  st = __builtin_amdgcn_mfma_f32_32x32x16_bf16(k2, q2f, st, 0, 0, 0);
  st = __builtin_amdgcn_mfma_f32_32x32x16_bf16(k3, q3f, st, 0, 0, 0);
#pragma unroll
  for (int r = 0; r < 16; ++r) st[r] *= SC;
  if (diag) {  // mask kv_local > q_local
#pragma unroll
    for (int r = 0; r < 16; ++r) {
      int kvl = (r & 3) + 8 * (r >> 2) + 4 * hi;
      if (kvl > lq) st[r] = -1e30f;
    }
  }
  float tmax = st[0];
#pragma unroll
  for (int r = 1; r < 16; ++r) tmax = fmaxf(tmax, st[r]);
  float tm = fmaxf(tmax, __shfl_xor(tmax, 32));
  if (__any(tm > S.m + 8.f)) {  // T13 defer-max
    float mnew = fmaxf(S.m, tm);
    float alpha = __builtin_amdgcn_exp2f(S.m - mnew);
    S.m = mnew;
    S.OTlo *= alpha;
    S.OThi *= alpha;
    S.l *= alpha;
  }
  unsigned c[8];
  float rs = 0.f;
#pragma unroll
  for (int i = 0; i < 8; ++i) {
    float pa = __builtin_amdgcn_exp2f(st[2 * i] - S.m);
    float pb = __builtin_amdgcn_exp2f(st[2 * i + 1] - S.m);
    rs += pa + pb;
    c[i] = cvt_pk_bf16(pa, pb);
  }
  S.l += rs + __shfl_xor(rs, 32);
  unsigned pc[8];
#pragma unroll
  for (int i = 0; i < 8; ++i) pc[i] = __shfl_xor(c[i], 32);
  uint4 w1, w2;
  w1.x = hi ? pc[2] : c[0]; w1.y = hi ? pc[3] : c[1];
  w1.z = hi ? c[2] : pc[0]; w1.w = hi ? c[3] : pc[1];
  w2.x = hi ? pc[6] : c[4]; w2.y = hi ? pc[7] : c[5];
  w2.z = hi ? c[6] : pc[4]; w2.w = hi ? c[7] : pc[5];
  bf16x8 f1 = __builtin_bit_cast(bf16x8, w1);
  bf16x8 f2 = __builtin_bit_cast(bf16x8, w2);
  S.OTlo = __builtin_amdgcn_mfma_f32_32x32x16_bf16(v0, f1, S.OTlo, 0, 0, 0);
  S.OTlo = __builtin_amdgcn_mfma_f32_32x32x16_bf16(v1, f2, S.OTlo, 0, 0, 0);
  S.OThi = __builtin_amdgcn_mfma_f32_32x32x16_bf16(v2, f1, S.OThi, 0, 0, 0);
  S.OThi = __builtin_amdgcn_mfma_f32_32x32x16_bf16(v3, f2, S.OThi, 0, 0, 0);
}

__global__ __launch_bounds__(256, 2) void k_attn(const unsigned short* __restrict__ qkv,
                                                 const unsigned short* __restrict__ vt,
                                                 unsigned short* __restrict__ y) {
  const int bh = blockIdx.x, b = bh >> 4, h = bh & 15;
  const int wv = threadIdx.x >> 6, lane = threadIdx.x & 63;
  const int w = blockIdx.y * 4 + wv;  // 0..31
  const int lq = lane & 31, hi = lane >> 5;
  const int ntL = w, ntH = 63 - w;          // diagonal tile index per q-set
  const int q0L = w * 32, q0H = (63 - w) * 32;

  // Q fragments (B-operand): lane j=lq reads Q row q0+lq, k=ki*16+hi*8+e
  const unsigned short* qrowL = qkv + ((size_t)(b * TSEQ) + q0L + lq) * (3 * CDIM) + h * HDIM;
  const unsigned short* qrowH = qkv + ((size_t)(b * TSEQ) + q0H + lq) * (3 * CDIM) + h * HDIM;
  bf16x8 qL0 = *(const bf16x8*)(qrowL + 0 + hi * 8);
  bf16x8 qL1 = *(const bf16x8*)(qrowL + 16 + hi * 8);
  bf16x8 qL2 = *(const bf16x8*)(qrowL + 32 + hi * 8);
  bf16x8 qL3 = *(const bf16x8*)(qrowL + 48 + hi * 8);
  bf16x8 qH0 = *(const bf16x8*)(qrowH + 0 + hi * 8);
  bf16x8 qH1 = *(const bf16x8*)(qrowH + 16 + hi * 8);
  bf16x8 qH2 = *(const bf16x8*)(qrowH + 32 + hi * 8);
  bf16x8 qH3 = *(const bf16x8*)(qrowH + 48 + hi * 8);

  const unsigned short* kbase = qkv + ((size_t)(b * TSEQ) + lq) * (3 * CDIM) + CDIM + h * HDIM;
  const unsigned short* vbase = vt + ((size_t)bh * HDIM + lq) * TSEQ;  // V^T row d=lq

  QSt SL, SH;
#pragma unroll
  for (int r = 0; r < 16; ++r) {
    SL.OTlo[r] = 0.f; SL.OThi[r] = 0.f; SH.OTlo[r] = 0.f; SH.OThi[r] = 0.f;
  }
  SL.m = -1e30f; SL.l = 0.f; SH.m = -1e30f; SH.l = 0.f;

#define LOADKV(K0_, K1_, K2_, K3_, V0_, V1_, V2_, V3_, tt)                 \
  do {                                                                     \
    const unsigned short* kr_ = kbase + (size_t)(tt) * 32 * (3 * CDIM);    \
    K0_ = *(const bf16x8*)(kr_ + 0 + hi * 8);                              \
    K1_ = *(const bf16x8*)(kr_ + 16 + hi * 8);                             \
    K2_ = *(const bf16x8*)(kr_ + 32 + hi * 8);                             \
    K3_ = *(const bf16x8*)(kr_ + 48 + hi * 8);                             \
    const unsigned short* vr_ = vbase + (tt) * 32;                         \
    V0_ = *(const bf16x8*)(vr_ + hi * 8);                                  \
    V1_ = *(const bf16x8*)(vr_ + 16 + hi * 8);                             \
    V2_ = *(const bf16x8*)(vr_ + 32 * TSEQ + hi * 8);                      \
    V3_ = *(const bf16x8*)(vr_ + 32 * TSEQ + 16 + hi * 8);                 \
  } while (0)

  bf16x8 kA0, kA1, kA2, kA3, vA0, vA1, vA2, vA3;
  bf16x8 kB0, kB1, kB2, kB3, vB0, vB1, vB2, vB3;
  LOADKV(kA0, kA1, kA2, kA3, vA0, vA1, vA2, vA3, 0);
  for (int t = 0;; t += 2) {
    if (t + 1 <= ntH) LOADKV(kB0, kB1, kB2, kB3, vB0, vB1, vB2, vB3, t + 1);
    attn_qk_sm_pv(kA0, kA1, kA2, kA3, vA0, vA1, vA2, vA3,
                  qH0, qH1, qH2, qH3, SH, t == ntH, lq, hi);
    if (t <= ntL)
      attn_qk_sm_pv(kA0, kA1, kA2, kA3, vA0, vA1, vA2, vA3,
                    qL0, qL1, qL2, qL3, SL, t == ntL, lq, hi);
    if (t + 1 > ntH) break;
    if (t + 2 <= ntH) LOADKV(kA0, kA1, kA2, kA3, vA0, vA1, vA2, vA3, t + 2);
    attn_qk_sm_pv(kB0, kB1, kB2, kB3, vB0, vB1, vB2, vB3,
                  qH0, qH1, qH2, qH3, SH, t + 1 == ntH, lq, hi);
    if (t + 1 <= ntL)
      attn_qk_sm_pv(kB0, kB1, kB2, kB3, vB0, vB1, vB2, vB3,
                    qL0, qL1, qL2, qL3, SL, t + 1 == ntL, lq, hi);
    if (t + 2 > ntH) break;
  }
#undef LOADKV

  // finalize both q-sets: O^T col q = lq, rows d per acc layout
  {
    float inv = 1.f / SH.l;
    unsigned short* yrow = y + ((size_t)(b * TSEQ) + q0H + lq) * CDIM + h * HDIM;
#pragma unroll
    for (int r = 0; r < 16; r += 2) {
      int d = (r & 3) + 8 * (r >> 2) + 4 * hi;
      unsigned lo0 = f2bf(SH.OTlo[r] * inv), lo1 = f2bf(SH.OTlo[r + 1] * inv);
      *(unsigned*)(yrow + d) = lo0 | (lo1 << 16);
      unsigned h0 = f2bf(SH.OThi[r] * inv), h1 = f2bf(SH.OThi[r + 1] * inv);
      *(unsigned*)(yrow + 32 + d) = h0 | (h1 << 16);
    }
  }
  {
    float inv = 1.f / SL.l;
    unsigned short* yrow = y + ((size_t)(b * TSEQ) + q0L + lq) * CDIM + h * HDIM;
#pragma unroll
    for (int r = 0; r < 16; r += 2) {
      int d = (r & 3) + 8 * (r >> 2) + 4 * hi;
      unsigned lo0 = f2bf(SL.OTlo[r] * inv), lo1 = f2bf(SL.OTlo[r + 1] * inv);
      *(unsigned*)(yrow + d) = lo0 | (lo1 << 16);
      unsigned h0 = f2bf(SL.OThi[r] * inv), h1 = f2bf(SL.OThi[r + 1] * inv);
      *(unsigned*)(yrow + 32 + d) = h0 | (h1 << 16);
    }
  }
}

// ---------------- launch
extern "C" void kernel_launch(void* const* d_in, const int* in_sizes, int n_in,
                              void* d_out, int out_size, void* d_ws, size_t ws_size,
                              hipStream_t stream) {
  const float* x = (const float*)d_in[0];
  const float* ln1_w = (const float*)d_in[1];
  const float* ln1_b = (const float*)d_in[2];
  const float* attn_w = (const float*)d_in[3];
  const float* attn_b = (const float*)d_in[4];
  const float* proj_w = (const float*)d_in[5];
  const float* proj_b = (const float*)d_in[6];
  const float* ln2_w = (const float*)d_in[7];
  const float* ln2_b = (const float*)d_in[8];
  const float* fc_w = (const float*)d_in[9];
  const float* fc_b = (const float*)d_in[10];
  const float* fc_proj_w = (const float*)d_in[11];
  const float* fc_proj_b = (const float*)d_in[12];

  char* ws = (char*)d_ws;
  // workspace layout (bytes)
  unsigned short* wt_attn = (unsigned short*)(ws + 0);           // [3072][1024] bf16, 6.29MB
  unsigned short* wt_proj = (unsigned short*)(ws + 6291456);     // [1024][1024]
  unsigned short* wt_fc = (unsigned short*)(ws + 8388608);       // [4096][1024]
  unsigned short* wt_fcp = (unsigned short*)(ws + 16777216);     // [1024][4096]
  float* x1 = (float*)(ws + 25165824);                           // [8192][1024] fp32
  unsigned short* hbuf = (unsigned short*)(ws + 58720256);       // [8192][1024] bf16 (ln1 out, reused for ln2 out)
  unsigned short* ybuf = (unsigned short*)(ws + 75497472);       // [8192][1024] bf16
  unsigned short* qkvb = (unsigned short*)(ws + 92274688);       // [8192][3072] bf16
  unsigned short* vtb = (unsigned short*)(ws + 142606336);       // [64][64][2048] bf16
  unsigned short* gbuf = (unsigned short*)(ws + 92274688);       // [8192][4096] bf16, aliases qkv+vt (dead by then)

  // 1. weight transposes (fp32 [K][N] -> bf16 [N][K])
  k_wtrans<<<dim3(3072 / 32, 1024 / 32), 256, 0, stream>>>(attn_w, wt_attn, 1024, 3072);
  k_wtrans<<<dim3(1024 / 32, 1024 / 32), 256, 0, stream>>>(proj_w, wt_proj, 1024, 1024);
  k_wtrans<<<dim3(4096 / 32, 1024 / 32), 256, 0, stream>>>(fc_w, wt_fc, 1024, 4096);
  k_wtrans<<<dim3(1024 / 32, 4096 / 32), 256, 0, stream>>>(fc_proj_w, wt_fcp, 4096, 1024);

  // 2. LN1: x -> hbuf (bf16)
  k_ln<<<NROWS, 256, 0, stream>>>(x, ln1_w, ln1_b, hbuf);

  // 3. qkv = h @ attn_w + attn_b -> bf16
  k_gemm<0><<<dim3(3072 / 128, NROWS / 128), 256, 0, stream>>>(
      hbuf, wt_attn, attn_b, nullptr, qkvb, NROWS, 3072, 1024);

  // 4. V^T
  k_build_vt<<<dim3(64, TSEQ / 64), 256, 0, stream>>>(qkvb, vtb);

  // 5. flash attention -> ybuf  (paired q-tiles: grid.y = T/32/2/4 = 8)
  k_attn<<<dim3(64, 8), 256, 0, stream>>>(qkvb, vtb, ybuf);

  // 6. x1 = x + y @ proj_w + proj_b (fp32)
  k_gemm<2><<<dim3(1024 / 128, NROWS / 128), 256, 0, stream>>>(
      ybuf, wt_proj, proj_b, x, x1, NROWS, 1024, 1024);

  // 7. LN2: x1 -> hbuf (bf16)
  k_ln<<<NROWS, 256, 0, stream>>>(x1, ln2_w, ln2_b, hbuf);

  // 8. g = gelu(h @ fc_w + fc_b) -> bf16
  k_gemm<1><<<dim3(4096 / 128, NROWS / 128), 256, 0, stream>>>(
      hbuf, wt_fc, fc_b, nullptr, gbuf, NROWS, 4096, 1024);

  // 9. out = x1 + g @ fc_proj_w + fc_proj_b (fp32)
  k_gemm<2><<<dim3(1024 / 128, NROWS / 128), 256, 0, stream>>>(
      gbuf, wt_fcp, fc_proj_b, x1, (float*)d_out, NROWS, 1024, 4096);
}

// Round 4
// 417.319 us; speedup vs baseline: 1.5102x; 1.1520x over previous
//
#include <hip/hip_runtime.h>
#include <stdint.h>

// Problem constants (B=4, T=2048, C=1024, H=16, HD=64)
#define TSEQ 2048
#define CDIM 1024
#define NHEAD 16
#define HDIM 64
#define NROWS 8192  // B*T

typedef __bf16 bf16x8 __attribute__((ext_vector_type(8)));
typedef float f32x4 __attribute__((ext_vector_type(4)));
typedef float f32x16 __attribute__((ext_vector_type(16)));

__device__ __forceinline__ unsigned short f2bf(float f) {
  unsigned u = __builtin_bit_cast(unsigned, f);
  u = u + 0x7fffu + ((u >> 16) & 1u);
  return (unsigned short)(u >> 16);
}

__device__ __forceinline__ unsigned cvt_pk_bf16(float a, float b) {
  unsigned r;
  asm("v_cvt_pk_bf16_f32 %0, %1, %2" : "=v"(r) : "v"(a), "v"(b));
  return r;
}

__device__ __forceinline__ float gelu_f(float x) {
  float x3 = x * x * x;
  float z = 0.7978845608028654f * (x + 0.044715f * x3);
  float e = __expf(2.f * z);
  float t = 1.f - 2.f / (e + 1.f);
  return 0.5f * x * (1.f + t);
}

// async 16B global->LDS (lds dest must be wave-uniform; HW adds lane*16)
__device__ __forceinline__ void ldg_lds16(void* lds, const void* gsrc) {
  __builtin_amdgcn_global_load_lds(
      (__attribute__((address_space(1))) unsigned int*)(uintptr_t)gsrc,
      (__attribute__((address_space(3))) unsigned int*)lds,
      16, 0, 0);
}

// ---------------- weight transpose+convert: W fp32 [K][N] -> Wt bf16 [N][K]
__global__ __launch_bounds__(256) void k_wtrans(const float* __restrict__ W,
                                                unsigned short* __restrict__ Wt,
                                                int K, int N) {
  __shared__ unsigned short tl[32][40];
  int n0 = blockIdx.x * 32, k0 = blockIdx.y * 32;
  int tid = threadIdx.x;
  int r = tid >> 3, c4 = (tid & 7) * 4;
  float4 v = *(const float4*)(W + (size_t)(k0 + r) * N + n0 + c4);
  ushort4 o;
  o.x = f2bf(v.x); o.y = f2bf(v.y); o.z = f2bf(v.z); o.w = f2bf(v.w);
  *(ushort4*)&tl[r][c4] = o;
  __syncthreads();
  int n = tid >> 3, k4 = (tid & 7) * 4;
  ushort4 w;
  w.x = tl[k4 + 0][n]; w.y = tl[k4 + 1][n]; w.z = tl[k4 + 2][n]; w.w = tl[k4 + 3][n];
  *(ushort4*)(Wt + (size_t)(n0 + n) * K + k0 + k4) = w;
}

// ---------------- layernorm: fp32 [rows][1024] -> bf16 [rows][1024]
__global__ __launch_bounds__(256) void k_ln(const float* __restrict__ x,
                                            const float* __restrict__ w,
                                            const float* __restrict__ b,
                                            unsigned short* __restrict__ out) {
  int row = blockIdx.x;
  int tid = threadIdx.x;
  const float* xr = x + (size_t)row * CDIM;
  float4 v = *(const float4*)(xr + tid * 4);
  float s = v.x + v.y + v.z + v.w;
  float s2 = v.x * v.x + v.y * v.y + v.z * v.z + v.w * v.w;
#pragma unroll
  for (int off = 32; off; off >>= 1) {
    s += __shfl_xor(s, off);
    s2 += __shfl_xor(s2, off);
  }
  __shared__ float rbuf[8];
  int wv = tid >> 6, lane = tid & 63;
  if (lane == 0) { rbuf[wv] = s; rbuf[4 + wv] = s2; }
  __syncthreads();
  float S1 = rbuf[0] + rbuf[1] + rbuf[2] + rbuf[3];
  float S2 = rbuf[4] + rbuf[5] + rbuf[6] + rbuf[7];
  float mean = S1 * (1.f / CDIM);
  float var = S2 * (1.f / CDIM) - mean * mean;
  float rstd = rsqrtf(var + 1e-5f);
  float4 wv4 = *(const float4*)(w + tid * 4);
  float4 bv4 = *(const float4*)(b + tid * 4);
  ushort4 o;
  o.x = f2bf((v.x - mean) * rstd * wv4.x + bv4.x);
  o.y = f2bf((v.y - mean) * rstd * wv4.y + bv4.y);
  o.z = f2bf((v.z - mean) * rstd * wv4.z + bv4.z);
  o.w = f2bf((v.w - mean) * rstd * wv4.w + bv4.w);
  *(ushort4*)(out + (size_t)row * CDIM + tid * 4) = o;
}

// ---------------- bf16 GEMM, pipelined: C[M,N] = A[M,K] @ Bt[N,K]^T (+epilogue)
// BM=128, BN=256, BK=64; 8 waves (2Mx4N), per-wave 64x64; ring-3 LDS (144KB);
// counted vmcnt(6), raw s_barrier, st_16x32 swizzle, setprio MFMA clusters.
// EPI 0: +bias -> bf16; EPI 1: gelu(+bias) -> bf16; EPI 2: +bias+resid -> fp32
template <int EPI>
__global__ __launch_bounds__(512, 2)
void k_gemm8(const unsigned short* __restrict__ A,
             const unsigned short* __restrict__ Bt,
             const float* __restrict__ bias,
             const float* __restrict__ resid,
             void* __restrict__ Cout,
             int M, int N, int K) {
  __shared__ __align__(16) unsigned short lds[3 * 24576];  // 3 x (A 16KB + B 32KB)
  const int tid = threadIdx.x;
  const int wid = tid >> 6, lane = tid & 63;
  const int wm = wid >> 2, wn = wid & 3;
  const int fr = lane & 15, fq = lane >> 4;

  // XCD-aware bijective swizzle (m204) of flat block id
  const int gx = gridDim.x;
  int flat = blockIdx.y * gx + blockIdx.x;
  {
    const int nwg = gx * gridDim.y;
    int q = nwg >> 3, r = nwg & 7;
    int xcd = flat & 7, idx = flat >> 3;
    flat = (xcd < r ? xcd * (q + 1) : r * (q + 1) + (xcd - r) * q) + idx;
  }
  const int bx = flat % gx, by = flat / gx;
  const long brow = (long)by * 128, bcol = (long)bx * 256;

  // staging: per-lane pre-swizzled global source (st_16x32: byte ^= ((byte>>9)&1)<<5)
  const int lrow = lane >> 3;                                        // row in 8-row chunk
  const int kby = ((lane & 7) << 4) ^ (((lane >> 5) & 1) << 5);      // swizzled byte-in-row
  const char* gA = (const char*)(A + ((size_t)(brow + wid * 16 + lrow)) * K) + kby;
  const char* gB = (const char*)(Bt + ((size_t)(bcol + wid * 32 + lrow)) * K) + kby;

  const int NT = K >> 6;

#define STAGE_A(i, t, bf_)                                              \
  ldg_lds16((char*)(lds + (bf_) * 24576) + (wid * 2 + (i)) * 1024,      \
            gA + ((size_t)(i) * 8 * K + (size_t)(t) * 64) * 2)
#define STAGE_B(j, t, bf_)                                              \
  ldg_lds16((char*)(lds + (bf_) * 24576 + 8192) + (wid * 4 + (j)) * 1024, \
            gB + ((size_t)(j) * 8 * K + (size_t)(t) * 64) * 2)

  // prologue: stage tiles 0 and 1 (6 loads each, in tile order)
  STAGE_A(0, 0, 0); STAGE_A(1, 0, 0);
  STAGE_B(0, 0, 0); STAGE_B(1, 0, 0); STAGE_B(2, 0, 0); STAGE_B(3, 0, 0);
  STAGE_A(0, 1, 1); STAGE_A(1, 1, 1);
  STAGE_B(0, 1, 1); STAGE_B(1, 1, 1); STAGE_B(2, 1, 1); STAGE_B(3, 1, 1);

  f32x4 acc[4][4];
  const f32x4 vzero = {0.f, 0.f, 0.f, 0.f};
#pragma unroll
  for (int m = 0; m < 4; ++m)
#pragma unroll
    for (int n = 0; n < 4; ++n) acc[m][n] = vzero;

  const int swz = (fq << 4) ^ ((fr & 4) << 3);  // swizzled k-slot byte offset
  int buf = 0;
  for (int t = 0; t < NT; ++t) {
    if (t + 1 < NT) asm volatile("s_waitcnt vmcnt(6)" ::: "memory");
    else            asm volatile("s_waitcnt vmcnt(0)" ::: "memory");
    __builtin_amdgcn_s_barrier();
    __builtin_amdgcn_sched_barrier(0);
    const char* pA = (const char*)(lds + buf * 24576);
    const char* pB = pA + 16384;
    int nbuf = buf + 2; if (nbuf >= 3) nbuf -= 3;
    // ---- phase 0: stage 3, read B(all)+A(m=0,1), 16 MFMA
    if (t + 2 < NT) { STAGE_A(0, t + 2, nbuf); STAGE_A(1, t + 2, nbuf); STAGE_B(0, t + 2, nbuf); }
    bf16x8 bfrag[4][2];
#pragma unroll
    for (int n = 0; n < 4; ++n)
#pragma unroll
      for (int kh = 0; kh < 2; ++kh)
        bfrag[n][kh] = *(const bf16x8*)(pB + (wn * 64 + n * 16 + fr) * 128 + kh * 64 + swz);
    bf16x8 af01[2][2];
#pragma unroll
    for (int m = 0; m < 2; ++m)
#pragma unroll
      for (int kh = 0; kh < 2; ++kh)
        af01[m][kh] = *(const bf16x8*)(pA + (wm * 64 + m * 16 + fr) * 128 + kh * 64 + swz);
    __builtin_amdgcn_s_setprio(1);
#pragma unroll
    for (int m = 0; m < 2; ++m)
#pragma unroll
      for (int n = 0; n < 4; ++n)
#pragma unroll
        for (int kh = 0; kh < 2; ++kh)
          acc[m][n] = __builtin_amdgcn_mfma_f32_16x16x32_bf16(af01[m][kh], bfrag[n][kh], acc[m][n], 0, 0, 0);
    __builtin_amdgcn_s_setprio(0);
    // ---- phase 1: stage 3, read A(m=2,3), 16 MFMA
    __builtin_amdgcn_s_barrier();
    if (t + 2 < NT) { STAGE_B(1, t + 2, nbuf); STAGE_B(2, t + 2, nbuf); STAGE_B(3, t + 2, nbuf); }
    bf16x8 af23[2][2];
#pragma unroll
    for (int m = 0; m < 2; ++m)
#pragma unroll
      for (int kh = 0; kh < 2; ++kh)
        af23[m][kh] = *(const bf16x8*)(pA + (wm * 64 + (m + 2) * 16 + fr) * 128 + kh * 64 + swz);
    __builtin_amdgcn_s_setprio(1);
#pragma unroll
    for (int m = 0; m < 2; ++m)
#pragma unroll
      for (int n = 0; n < 4; ++n)
#pragma unroll
        for (int kh = 0; kh < 2; ++kh)
          acc[m + 2][n] = __builtin_amdgcn_mfma_f32_16x16x32_bf16(af23[m][kh], bfrag[n][kh], acc[m + 2][n], 0, 0, 0);
    __builtin_amdgcn_s_setprio(0);
    buf = buf + 1; if (buf == 3) buf = 0;
  }
#undef STAGE_A
#undef STAGE_B

  // epilogue
#pragma unroll
  for (int m = 0; m < 4; ++m) {
    long row = brow + wm * 64 + m * 16 + fq * 4;
#pragma unroll
    for (int n = 0; n < 4; ++n) {
      long col = bcol + wn * 64 + n * 16 + fr;
      float bv = bias[col];
#pragma unroll
      for (int r = 0; r < 4; ++r) {
        float v = acc[m][n][r] + bv;
        long idx = (row + r) * (long)N + col;
        if (EPI == 0) {
          ((unsigned short*)Cout)[idx] = f2bf(v);
        } else if (EPI == 1) {
          ((unsigned short*)Cout)[idx] = f2bf(gelu_f(v));
        } else {
          ((float*)Cout)[idx] = v + resid[idx];
        }
      }
    }
  }
}

// ---------------- build V^T: qkv bf16 [8192][3072] (v at col 2048+h*64) -> vt [b,h,64,2048]
__global__ __launch_bounds__(256) void k_build_vt(const unsigned short* __restrict__ qkv,
                                                  unsigned short* __restrict__ vt) {
  __shared__ __align__(16) unsigned short tl[64][80];
  int bh = blockIdx.x, b = bh >> 4, h = bh & 15;
  int t0 = blockIdx.y * 64;
  int tid = threadIdx.x;
  int r = tid >> 2, cb = (tid & 3) * 16;
  const unsigned short* src =
      qkv + (size_t)(b * TSEQ + t0 + r) * (3 * CDIM) + 2 * CDIM + h * HDIM + cb;
  *(uint4*)&tl[r][cb] = *(const uint4*)src;
  *(uint4*)&tl[r][cb + 8] = *(const uint4*)(src + 8);
  __syncthreads();
  int d = tid >> 2, tb = (tid & 3) * 16;
  union { unsigned short u[16]; uint4 v[2]; } o;
#pragma unroll
  for (int j = 0; j < 16; ++j) o.u[j] = tl[tb + j][d];
  unsigned short* dst = vt + ((size_t)bh * HDIM + d) * TSEQ + t0 + tb;
  *(uint4*)dst = o.v[0];
  *(uint4*)(dst + 8) = o.v[1];
}

// ---------------- flash attention (causal), swapped-QK^T 32x32, paired q-tiles.
struct QSt {
  f32x16 OTlo, OThi;
  float m, l;
};

__device__ __forceinline__ void attn_qk_sm_pv(
    const bf16x8& k0, const bf16x8& k1, const bf16x8& k2, const bf16x8& k3,
    const bf16x8& v0, const bf16x8& v1, const bf16x8& v2, const bf16x8& v3,
    const bf16x8& q0f, const bf16x8& q1f, const bf16x8& q2f, const bf16x8& q3f,
    QSt& S, bool diag, int lq, int hi) {
  const float SC = 0.125f * 1.44269504088896f;  // 1/sqrt(HD) * log2(e)
  f32x16 st;
#pragma unroll
  for (int r = 0; r < 16; ++r) st[r] = 0.f;
  st = __builtin_amdgcn_mfma_f32_32x32x16_bf16(k0, q0f, st, 0, 0, 0);
  st = __builtin_amdgcn_mfma_f32_32x32x16_bf16(k1, q1f, st, 0, 0, 0);
  st = __builtin_amdgcn_mfma_f32_32x32x16_bf16(k2, q2f, st, 0, 0, 0);
  st = __builtin_amdgcn_mfma_f32_32x32x16_bf16(k3, q3f, st, 0, 0, 0);
#pragma unroll
  for (int r = 0; r < 16; ++r) st[r] *= SC;
  if (diag) {
#pragma unroll
    for (int r = 0; r < 16; ++r) {
      int kvl = (r & 3) + 8 * (r >> 2) + 4 * hi;
      if (kvl > lq) st[r] = -1e30f;
    }
  }
  float tmax = st[0];
#pragma unroll
  for (int r = 1; r < 16; ++r) tmax = fmaxf(tmax, st[r]);
  float tm = fmaxf(tmax, __shfl_xor(tmax, 32));
  if (__any(tm > S.m + 8.f)) {  // T13 defer-max
    float mnew = fmaxf(S.m, tm);
    float alpha = __builtin_amdgcn_exp2f(S.m - mnew);
    S.m = mnew;
    S.OTlo *= alpha;
    S.OThi *= alpha;
    S.l *= alpha;
  }
  unsigned c[8];
  float rs = 0.f;
#pragma unroll
  for (int i = 0; i < 8; ++i) {
    float pa = __builtin_amdgcn_exp2f(st[2 * i] - S.m);
    float pb = __builtin_amdgcn_exp2f(st[2 * i + 1] - S.m);
    rs += pa + pb;
    c[i] = cvt_pk_bf16(pa, pb);
  }
  S.l += rs + __shfl_xor(rs, 32);
  unsigned pc[8];
#pragma unroll
  for (int i = 0; i < 8; ++i) pc[i] = __shfl_xor(c[i], 32);
  uint4 w1, w2;
  w1.x = hi ? pc[2] : c[0]; w1.y = hi ? pc[3] : c[1];
  w1.z = hi ? c[2] : pc[0]; w1.w = hi ? c[3] : pc[1];
  w2.x = hi ? pc[6] : c[4]; w2.y = hi ? pc[7] : c[5];
  w2.z = hi ? c[6] : pc[4]; w2.w = hi ? c[7] : pc[5];
  bf16x8 f1 = __builtin_bit_cast(bf16x8, w1);
  bf16x8 f2 = __builtin_bit_cast(bf16x8, w2);
  S.OTlo = __builtin_amdgcn_mfma_f32_32x32x16_bf16(v0, f1, S.OTlo, 0, 0, 0);
  S.OTlo = __builtin_amdgcn_mfma_f32_32x32x16_bf16(v1, f2, S.OTlo, 0, 0, 0);
  S.OThi = __builtin_amdgcn_mfma_f32_32x32x16_bf16(v2, f1, S.OThi, 0, 0, 0);
  S.OThi = __builtin_amdgcn_mfma_f32_32x32x16_bf16(v3, f2, S.OThi, 0, 0, 0);
}

__global__ __launch_bounds__(256, 2) void k_attn(const unsigned short* __restrict__ qkv,
                                                 const unsigned short* __restrict__ vt,
                                                 unsigned short* __restrict__ y) {
  const int bh = blockIdx.x, b = bh >> 4, h = bh & 15;
  const int wv = threadIdx.x >> 6, lane = threadIdx.x & 63;
  const int w = blockIdx.y * 4 + wv;  // 0..31
  const int lq = lane & 31, hi = lane >> 5;
  const int ntL = w, ntH = 63 - w;
  const int q0L = w * 32, q0H = (63 - w) * 32;

  const unsigned short* qrowL = qkv + ((size_t)(b * TSEQ) + q0L + lq) * (3 * CDIM) + h * HDIM;
  const unsigned short* qrowH = qkv + ((size_t)(b * TSEQ) + q0H + lq) * (3 * CDIM) + h * HDIM;
  bf16x8 qL0 = *(const bf16x8*)(qrowL + 0 + hi * 8);
  bf16x8 qL1 = *(const bf16x8*)(qrowL + 16 + hi * 8);
  bf16x8 qL2 = *(const bf16x8*)(qrowL + 32 + hi * 8);
  bf16x8 qL3 = *(const bf16x8*)(qrowL + 48 + hi * 8);
  bf16x8 qH0 = *(const bf16x8*)(qrowH + 0 + hi * 8);
  bf16x8 qH1 = *(const bf16x8*)(qrowH + 16 + hi * 8);
  bf16x8 qH2 = *(const bf16x8*)(qrowH + 32 + hi * 8);
  bf16x8 qH3 = *(const bf16x8*)(qrowH + 48 + hi * 8);

  const unsigned short* kbase = qkv + ((size_t)(b * TSEQ) + lq) * (3 * CDIM) + CDIM + h * HDIM;
  const unsigned short* vbase = vt + ((size_t)bh * HDIM + lq) * TSEQ;

  QSt SL, SH;
#pragma unroll
  for (int r = 0; r < 16; ++r) {
    SL.OTlo[r] = 0.f; SL.OThi[r] = 0.f; SH.OTlo[r] = 0.f; SH.OThi[r] = 0.f;
  }
  SL.m = -1e30f; SL.l = 0.f; SH.m = -1e30f; SH.l = 0.f;

#define LOADKV(K0_, K1_, K2_, K3_, V0_, V1_, V2_, V3_, tt)                 \
  do {                                                                     \
    const unsigned short* kr_ = kbase + (size_t)(tt) * 32 * (3 * CDIM);    \
    K0_ = *(const bf16x8*)(kr_ + 0 + hi * 8);                              \
    K1_ = *(const bf16x8*)(kr_ + 16 + hi * 8);                             \
    K2_ = *(const bf16x8*)(kr_ + 32 + hi * 8);                             \
    K3_ = *(const bf16x8*)(kr_ + 48 + hi * 8);                             \
    const unsigned short* vr_ = vbase + (tt) * 32;                         \
    V0_ = *(const bf16x8*)(vr_ + hi * 8);                                  \
    V1_ = *(const bf16x8*)(vr_ + 16 + hi * 8);                             \
    V2_ = *(const bf16x8*)(vr_ + 32 * TSEQ + hi * 8);                      \
    V3_ = *(const bf16x8*)(vr_ + 32 * TSEQ + 16 + hi * 8);                 \
  } while (0)

  bf16x8 kA0, kA1, kA2, kA3, vA0, vA1, vA2, vA3;
  bf16x8 kB0, kB1, kB2, kB3, vB0, vB1, vB2, vB3;
  LOADKV(kA0, kA1, kA2, kA3, vA0, vA1, vA2, vA3, 0);
  for (int t = 0;; t += 2) {
    if (t + 1 <= ntH) LOADKV(kB0, kB1, kB2, kB3, vB0, vB1, vB2, vB3, t + 1);
    attn_qk_sm_pv(kA0, kA1, kA2, kA3, vA0, vA1, vA2, vA3,
                  qH0, qH1, qH2, qH3, SH, t == ntH, lq, hi);
    if (t <= ntL)
      attn_qk_sm_pv(kA0, kA1, kA2, kA3, vA0, vA1, vA2, vA3,
                    qL0, qL1, qL2, qL3, SL, t == ntL, lq, hi);
    if (t + 1 > ntH) break;
    if (t + 2 <= ntH) LOADKV(kA0, kA1, kA2, kA3, vA0, vA1, vA2, vA3, t + 2);
    attn_qk_sm_pv(kB0, kB1, kB2, kB3, vB0, vB1, vB2, vB3,
                  qH0, qH1, qH2, qH3, SH, t + 1 == ntH, lq, hi);
    if (t + 1 <= ntL)
      attn_qk_sm_pv(kB0, kB1, kB2, kB3, vB0, vB1, vB2, vB3,
                    qL0, qL1, qL2, qL3, SL, t + 1 == ntL, lq, hi);
    if (t + 2 > ntH) break;
  }
#undef LOADKV

  {
    float inv = 1.f / SH.l;
    unsigned short* yrow = y + ((size_t)(b * TSEQ) + q0H + lq) * CDIM + h * HDIM;
#pragma unroll
    for (int r = 0; r < 16; r += 2) {
      int d = (r & 3) + 8 * (r >> 2) + 4 * hi;
      unsigned lo0 = f2bf(SH.OTlo[r] * inv), lo1 = f2bf(SH.OTlo[r + 1] * inv);
      *(unsigned*)(yrow + d) = lo0 | (lo1 << 16);
      unsigned h0 = f2bf(SH.OThi[r] * inv), h1 = f2bf(SH.OThi[r + 1] * inv);
      *(unsigned*)(yrow + 32 + d) = h0 | (h1 << 16);
    }
  }
  {
    float inv = 1.f / SL.l;
    unsigned short* yrow = y + ((size_t)(b * TSEQ) + q0L + lq) * CDIM + h * HDIM;
#pragma unroll
    for (int r = 0; r < 16; r += 2) {
      int d = (r & 3) + 8 * (r >> 2) + 4 * hi;
      unsigned lo0 = f2bf(SL.OTlo[r] * inv), lo1 = f2bf(SL.OTlo[r + 1] * inv);
      *(unsigned*)(yrow + d) = lo0 | (lo1 << 16);
      unsigned h0 = f2bf(SL.OThi[r] * inv), h1 = f2bf(SL.OThi[r + 1] * inv);
      *(unsigned*)(yrow + 32 + d) = h0 | (h1 << 16);
    }
  }
}

// ---------------- launch
extern "C" void kernel_launch(void* const* d_in, const int* in_sizes, int n_in,
                              void* d_out, int out_size, void* d_ws, size_t ws_size,
                              hipStream_t stream) {
  const float* x = (const float*)d_in[0];
  const float* ln1_w = (const float*)d_in[1];
  const float* ln1_b = (const float*)d_in[2];
  const float* attn_w = (const float*)d_in[3];
  const float* attn_b = (const float*)d_in[4];
  const float* proj_w = (const float*)d_in[5];
  const float* proj_b = (const float*)d_in[6];
  const float* ln2_w = (const float*)d_in[7];
  const float* ln2_b = (const float*)d_in[8];
  const float* fc_w = (const float*)d_in[9];
  const float* fc_b = (const float*)d_in[10];
  const float* fc_proj_w = (const float*)d_in[11];
  const float* fc_proj_b = (const float*)d_in[12];

  char* ws = (char*)d_ws;
  unsigned short* wt_attn = (unsigned short*)(ws + 0);           // [3072][1024] bf16
  unsigned short* wt_proj = (unsigned short*)(ws + 6291456);     // [1024][1024]
  unsigned short* wt_fc = (unsigned short*)(ws + 8388608);       // [4096][1024]
  unsigned short* wt_fcp = (unsigned short*)(ws + 16777216);     // [1024][4096]
  float* x1 = (float*)(ws + 25165824);                           // [8192][1024] fp32
  unsigned short* hbuf = (unsigned short*)(ws + 58720256);       // [8192][1024] bf16
  unsigned short* ybuf = (unsigned short*)(ws + 75497472);       // [8192][1024] bf16
  unsigned short* qkvb = (unsigned short*)(ws + 92274688);       // [8192][3072] bf16
  unsigned short* vtb = (unsigned short*)(ws + 142606336);       // [64][64][2048] bf16
  unsigned short* gbuf = (unsigned short*)(ws + 92274688);       // [8192][4096] bf16 (aliases qkv+vt)

  // 1. weight transposes
  k_wtrans<<<dim3(3072 / 32, 1024 / 32), 256, 0, stream>>>(attn_w, wt_attn, 1024, 3072);
  k_wtrans<<<dim3(1024 / 32, 1024 / 32), 256, 0, stream>>>(proj_w, wt_proj, 1024, 1024);
  k_wtrans<<<dim3(4096 / 32, 1024 / 32), 256, 0, stream>>>(fc_w, wt_fc, 1024, 4096);
  k_wtrans<<<dim3(1024 / 32, 4096 / 32), 256, 0, stream>>>(fc_proj_w, wt_fcp, 4096, 1024);

  // 2. LN1
  k_ln<<<NROWS, 256, 0, stream>>>(x, ln1_w, ln1_b, hbuf);

  // 3. qkv = h @ attn_w + attn_b
  k_gemm8<0><<<dim3(3072 / 256, NROWS / 128), 512, 0, stream>>>(
      hbuf, wt_attn, attn_b, nullptr, qkvb, NROWS, 3072, 1024);

  // 4. V^T
  k_build_vt<<<dim3(64, TSEQ / 64), 256, 0, stream>>>(qkvb, vtb);

  // 5. flash attention
  k_attn<<<dim3(64, 8), 256, 0, stream>>>(qkvb, vtb, ybuf);

  // 6. x1 = x + y @ proj_w + proj_b
  k_gemm8<2><<<dim3(1024 / 256, NROWS / 128), 512, 0, stream>>>(
      ybuf, wt_proj, proj_b, x, x1, NROWS, 1024, 1024);

  // 7. LN2
  k_ln<<<NROWS, 256, 0, stream>>>(x1, ln2_w, ln2_b, hbuf);

  // 8. g = gelu(h @ fc_w + fc_b)
  k_gemm8<1><<<dim3(4096 / 256, NROWS / 128), 512, 0, stream>>>(
      hbuf, wt_fc, fc_b, nullptr, gbuf, NROWS, 4096, 1024);

  // 9. out = x1 + g @ fc_proj_w + fc_proj_b
  k_gemm8<2><<<dim3(1024 / 256, NROWS / 128), 512, 0, stream>>>(
      gbuf, wt_fcp, fc_proj_b, x1, (float*)d_out, NROWS, 1024, 4096);
}

// Round 5
// 390.195 us; speedup vs baseline: 1.6152x; 1.0695x over previous
//
#include <hip/hip_runtime.h>
#include <stdint.h>

// Problem constants (B=4, T=2048, C=1024, H=16, HD=64)
#define TSEQ 2048
#define CDIM 1024
#define NHEAD 16
#define HDIM 64
#define NROWS 8192  // B*T

typedef __bf16 bf16x8 __attribute__((ext_vector_type(8)));
typedef float f32x4 __attribute__((ext_vector_type(4)));
typedef float f32x16 __attribute__((ext_vector_type(16)));

__device__ __forceinline__ unsigned short f2bf(float f) {
  unsigned u = __builtin_bit_cast(unsigned, f);
  u = u + 0x7fffu + ((u >> 16) & 1u);
  return (unsigned short)(u >> 16);
}

__device__ __forceinline__ unsigned cvt_pk_bf16(float a, float b) {
  unsigned r;
  asm("v_cvt_pk_bf16_f32 %0, %1, %2" : "=v"(r) : "v"(a), "v"(b));
  return r;
}

__device__ __forceinline__ float gelu_f(float x) {
  float x3 = x * x * x;
  float z = 0.7978845608028654f * (x + 0.044715f * x3);
  float e = __expf(2.f * z);
  float t = 1.f - 2.f / (e + 1.f);
  return 0.5f * x * (1.f + t);
}

// async 16B global->LDS (lds dest must be wave-uniform; HW adds lane*16)
__device__ __forceinline__ void ldg_lds16(void* lds, const void* gsrc) {
  __builtin_amdgcn_global_load_lds(
      (__attribute__((address_space(1))) unsigned int*)(uintptr_t)gsrc,
      (__attribute__((address_space(3))) unsigned int*)lds,
      16, 0, 0);
}

// ---------------- weight transpose+convert: W fp32 [K][N] -> Wt bf16 [N][K]
__global__ __launch_bounds__(256) void k_wtrans(const float* __restrict__ W,
                                                unsigned short* __restrict__ Wt,
                                                int K, int N) {
  __shared__ unsigned short tl[32][40];
  int n0 = blockIdx.x * 32, k0 = blockIdx.y * 32;
  int tid = threadIdx.x;
  int r = tid >> 3, c4 = (tid & 7) * 4;
  float4 v = *(const float4*)(W + (size_t)(k0 + r) * N + n0 + c4);
  ushort4 o;
  o.x = f2bf(v.x); o.y = f2bf(v.y); o.z = f2bf(v.z); o.w = f2bf(v.w);
  *(ushort4*)&tl[r][c4] = o;
  __syncthreads();
  int n = tid >> 3, k4 = (tid & 7) * 4;
  ushort4 w;
  w.x = tl[k4 + 0][n]; w.y = tl[k4 + 1][n]; w.z = tl[k4 + 2][n]; w.w = tl[k4 + 3][n];
  *(ushort4*)(Wt + (size_t)(n0 + n) * K + k0 + k4) = w;
}

// ---------------- layernorm: fp32 [rows][1024] -> bf16 [rows][1024]
__global__ __launch_bounds__(256) void k_ln(const float* __restrict__ x,
                                            const float* __restrict__ w,
                                            const float* __restrict__ b,
                                            unsigned short* __restrict__ out) {
  int row = blockIdx.x;
  int tid = threadIdx.x;
  const float* xr = x + (size_t)row * CDIM;
  float4 v = *(const float4*)(xr + tid * 4);
  float s = v.x + v.y + v.z + v.w;
  float s2 = v.x * v.x + v.y * v.y + v.z * v.z + v.w * v.w;
#pragma unroll
  for (int off = 32; off; off >>= 1) {
    s += __shfl_xor(s, off);
    s2 += __shfl_xor(s2, off);
  }
  __shared__ float rbuf[8];
  int wv = tid >> 6, lane = tid & 63;
  if (lane == 0) { rbuf[wv] = s; rbuf[4 + wv] = s2; }
  __syncthreads();
  float S1 = rbuf[0] + rbuf[1] + rbuf[2] + rbuf[3];
  float S2 = rbuf[4] + rbuf[5] + rbuf[6] + rbuf[7];
  float mean = S1 * (1.f / CDIM);
  float var = S2 * (1.f / CDIM) - mean * mean;
  float rstd = rsqrtf(var + 1e-5f);
  float4 wv4 = *(const float4*)(w + tid * 4);
  float4 bv4 = *(const float4*)(b + tid * 4);
  ushort4 o;
  o.x = f2bf((v.x - mean) * rstd * wv4.x + bv4.x);
  o.y = f2bf((v.y - mean) * rstd * wv4.y + bv4.y);
  o.z = f2bf((v.z - mean) * rstd * wv4.z + bv4.z);
  o.w = f2bf((v.w - mean) * rstd * wv4.w + bv4.w);
  *(ushort4*)(out + (size_t)row * CDIM + tid * 4) = o;
}

// ---------------- bf16 GEMM, pipelined: C[M,N] = A[M,K] @ Bt[N,K]^T (+epilogue)
// BM=128, BN=256, BK=64; 8 waves (2Mx4N), per-wave 64x64; ring-3 LDS (144KB);
// counted vmcnt(6), raw s_barrier, st_16x32 swizzle, setprio MFMA clusters.
// EPI 0: +bias -> bf16; EPI 1: gelu(+bias) -> bf16; EPI 2: +bias+resid -> fp32
template <int EPI>
__global__ __launch_bounds__(512, 2)
void k_gemm8(const unsigned short* __restrict__ A,
             const unsigned short* __restrict__ Bt,
             const float* __restrict__ bias,
             const float* __restrict__ resid,
             void* __restrict__ Cout,
             int M, int N, int K) {
  __shared__ __align__(16) unsigned short lds[3 * 24576];  // 3 x (A 16KB + B 32KB)
  const int tid = threadIdx.x;
  const int wid = tid >> 6, lane = tid & 63;
  const int wm = wid >> 2, wn = wid & 3;
  const int fr = lane & 15, fq = lane >> 4;

  // XCD-aware bijective swizzle (m204) of flat block id
  const int gx = gridDim.x;
  int flat = blockIdx.y * gx + blockIdx.x;
  {
    const int nwg = gx * gridDim.y;
    int q = nwg >> 3, r = nwg & 7;
    int xcd = flat & 7, idx = flat >> 3;
    flat = (xcd < r ? xcd * (q + 1) : r * (q + 1) + (xcd - r) * q) + idx;
  }
  const int bx = flat % gx, by = flat / gx;
  const long brow = (long)by * 128, bcol = (long)bx * 256;

  // staging: per-lane pre-swizzled global source (st_16x32: byte ^= ((byte>>9)&1)<<5)
  const int lrow = lane >> 3;                                        // row in 8-row chunk
  const int kby = ((lane & 7) << 4) ^ (((lane >> 5) & 1) << 5);      // swizzled byte-in-row
  const char* gA = (const char*)(A + ((size_t)(brow + wid * 16 + lrow)) * K) + kby;
  const char* gB = (const char*)(Bt + ((size_t)(bcol + wid * 32 + lrow)) * K) + kby;

  const int NT = K >> 6;

#define STAGE_A(i, t, bf_)                                              \
  ldg_lds16((char*)(lds + (bf_) * 24576) + (wid * 2 + (i)) * 1024,      \
            gA + ((size_t)(i) * 8 * K + (size_t)(t) * 64) * 2)
#define STAGE_B(j, t, bf_)                                              \
  ldg_lds16((char*)(lds + (bf_) * 24576 + 8192) + (wid * 4 + (j)) * 1024, \
            gB + ((size_t)(j) * 8 * K + (size_t)(t) * 64) * 2)

  // prologue: stage tiles 0 and 1 (6 loads each, in tile order)
  STAGE_A(0, 0, 0); STAGE_A(1, 0, 0);
  STAGE_B(0, 0, 0); STAGE_B(1, 0, 0); STAGE_B(2, 0, 0); STAGE_B(3, 0, 0);
  STAGE_A(0, 1, 1); STAGE_A(1, 1, 1);
  STAGE_B(0, 1, 1); STAGE_B(1, 1, 1); STAGE_B(2, 1, 1); STAGE_B(3, 1, 1);

  f32x4 acc[4][4];
  const f32x4 vzero = {0.f, 0.f, 0.f, 0.f};
#pragma unroll
  for (int m = 0; m < 4; ++m)
#pragma unroll
    for (int n = 0; n < 4; ++n) acc[m][n] = vzero;

  const int swz = (fq << 4) ^ ((fr & 4) << 3);  // swizzled k-slot byte offset
  int buf = 0;
  for (int t = 0; t < NT; ++t) {
    if (t + 1 < NT) asm volatile("s_waitcnt vmcnt(6)" ::: "memory");
    else            asm volatile("s_waitcnt vmcnt(0)" ::: "memory");
    __builtin_amdgcn_s_barrier();
    __builtin_amdgcn_sched_barrier(0);
    const char* pA = (const char*)(lds + buf * 24576);
    const char* pB = pA + 16384;
    int nbuf = buf + 2; if (nbuf >= 3) nbuf -= 3;
    // ---- phase 0: stage 3, read B(all)+A(m=0,1), 16 MFMA
    if (t + 2 < NT) { STAGE_A(0, t + 2, nbuf); STAGE_A(1, t + 2, nbuf); STAGE_B(0, t + 2, nbuf); }
    bf16x8 bfrag[4][2];
#pragma unroll
    for (int n = 0; n < 4; ++n)
#pragma unroll
      for (int kh = 0; kh < 2; ++kh)
        bfrag[n][kh] = *(const bf16x8*)(pB + (wn * 64 + n * 16 + fr) * 128 + kh * 64 + swz);
    bf16x8 af01[2][2];
#pragma unroll
    for (int m = 0; m < 2; ++m)
#pragma unroll
      for (int kh = 0; kh < 2; ++kh)
        af01[m][kh] = *(const bf16x8*)(pA + (wm * 64 + m * 16 + fr) * 128 + kh * 64 + swz);
    __builtin_amdgcn_s_setprio(1);
#pragma unroll
    for (int m = 0; m < 2; ++m)
#pragma unroll
      for (int n = 0; n < 4; ++n)
#pragma unroll
        for (int kh = 0; kh < 2; ++kh)
          acc[m][n] = __builtin_amdgcn_mfma_f32_16x16x32_bf16(af01[m][kh], bfrag[n][kh], acc[m][n], 0, 0, 0);
    __builtin_amdgcn_s_setprio(0);
    // ---- phase 1: stage 3, read A(m=2,3), 16 MFMA
    __builtin_amdgcn_s_barrier();
    if (t + 2 < NT) { STAGE_B(1, t + 2, nbuf); STAGE_B(2, t + 2, nbuf); STAGE_B(3, t + 2, nbuf); }
    bf16x8 af23[2][2];
#pragma unroll
    for (int m = 0; m < 2; ++m)
#pragma unroll
      for (int kh = 0; kh < 2; ++kh)
        af23[m][kh] = *(const bf16x8*)(pA + (wm * 64 + (m + 2) * 16 + fr) * 128 + kh * 64 + swz);
    __builtin_amdgcn_s_setprio(1);
#pragma unroll
    for (int m = 0; m < 2; ++m)
#pragma unroll
      for (int n = 0; n < 4; ++n)
#pragma unroll
        for (int kh = 0; kh < 2; ++kh)
          acc[m + 2][n] = __builtin_amdgcn_mfma_f32_16x16x32_bf16(af23[m][kh], bfrag[n][kh], acc[m + 2][n], 0, 0, 0);
    __builtin_amdgcn_s_setprio(0);
    buf = buf + 1; if (buf == 3) buf = 0;
  }
#undef STAGE_A
#undef STAGE_B

  // epilogue
#pragma unroll
  for (int m = 0; m < 4; ++m) {
    long row = brow + wm * 64 + m * 16 + fq * 4;
#pragma unroll
    for (int n = 0; n < 4; ++n) {
      long col = bcol + wn * 64 + n * 16 + fr;
      float bv = bias[col];
#pragma unroll
      for (int r = 0; r < 4; ++r) {
        float v = acc[m][n][r] + bv;
        long idx = (row + r) * (long)N + col;
        if (EPI == 0) {
          ((unsigned short*)Cout)[idx] = f2bf(v);
        } else if (EPI == 1) {
          ((unsigned short*)Cout)[idx] = f2bf(gelu_f(v));
        } else {
          ((float*)Cout)[idx] = v + resid[idx];
        }
      }
    }
  }
}

// ---------------- build V^T: qkv bf16 [8192][3072] (v at col 2048+h*64) -> vt [b,h,64,2048]
__global__ __launch_bounds__(256) void k_build_vt(const unsigned short* __restrict__ qkv,
                                                  unsigned short* __restrict__ vt) {
  __shared__ __align__(16) unsigned short tl[64][80];
  int bh = blockIdx.x, b = bh >> 4, h = bh & 15;
  int t0 = blockIdx.y * 64;
  int tid = threadIdx.x;
  int r = tid >> 2, cb = (tid & 3) * 16;
  const unsigned short* src =
      qkv + (size_t)(b * TSEQ + t0 + r) * (3 * CDIM) + 2 * CDIM + h * HDIM + cb;
  *(uint4*)&tl[r][cb] = *(const uint4*)src;
  *(uint4*)&tl[r][cb + 8] = *(const uint4*)(src + 8);
  __syncthreads();
  int d = tid >> 2, tb = (tid & 3) * 16;
  union { unsigned short u[16]; uint4 v[2]; } o;
#pragma unroll
  for (int j = 0; j < 16; ++j) o.u[j] = tl[tb + j][d];
  unsigned short* dst = vt + ((size_t)bh * HDIM + d) * TSEQ + t0 + tb;
  *(uint4*)dst = o.v[0];
  *(uint4*)(dst + 8) = o.v[1];
}

// ---------------- flash attention (causal), swapped-QK^T 32x32, paired q-tiles,
// block-shared LDS-staged K/V (chunk-column-major: bank-optimal, no swizzle needed).
struct QSt {
  f32x16 OTlo, OThi;
  float m, l;
};

__device__ __forceinline__ void attn_qk_sm_pv(
    const bf16x8& k0, const bf16x8& k1, const bf16x8& k2, const bf16x8& k3,
    const bf16x8& v0, const bf16x8& v1, const bf16x8& v2, const bf16x8& v3,
    const bf16x8& q0f, const bf16x8& q1f, const bf16x8& q2f, const bf16x8& q3f,
    QSt& S, bool diag, int lq, int hi) {
  const float SC = 0.125f * 1.44269504088896f;  // 1/sqrt(HD) * log2(e)
  f32x16 st;
#pragma unroll
  for (int r = 0; r < 16; ++r) st[r] = 0.f;
  st = __builtin_amdgcn_mfma_f32_32x32x16_bf16(k0, q0f, st, 0, 0, 0);
  st = __builtin_amdgcn_mfma_f32_32x32x16_bf16(k1, q1f, st, 0, 0, 0);
  st = __builtin_amdgcn_mfma_f32_32x32x16_bf16(k2, q2f, st, 0, 0, 0);
  st = __builtin_amdgcn_mfma_f32_32x32x16_bf16(k3, q3f, st, 0, 0, 0);
#pragma unroll
  for (int r = 0; r < 16; ++r) st[r] *= SC;
  if (diag) {
#pragma unroll
    for (int r = 0; r < 16; ++r) {
      int kvl = (r & 3) + 8 * (r >> 2) + 4 * hi;
      if (kvl > lq) st[r] = -1e30f;
    }
  }
  float tmax = st[0];
#pragma unroll
  for (int r = 1; r < 16; ++r) tmax = fmaxf(tmax, st[r]);
  float tm = fmaxf(tmax, __shfl_xor(tmax, 32));
  if (__any(tm > S.m + 8.f)) {  // T13 defer-max
    float mnew = fmaxf(S.m, tm);
    float alpha = __builtin_amdgcn_exp2f(S.m - mnew);
    S.m = mnew;
    S.OTlo *= alpha;
    S.OThi *= alpha;
    S.l *= alpha;
  }
  unsigned c[8];
  float rs = 0.f;
#pragma unroll
  for (int i = 0; i < 8; ++i) {
    float pa = __builtin_amdgcn_exp2f(st[2 * i] - S.m);
    float pb = __builtin_amdgcn_exp2f(st[2 * i + 1] - S.m);
    rs += pa + pb;
    c[i] = cvt_pk_bf16(pa, pb);
  }
  S.l += rs + __shfl_xor(rs, 32);
  unsigned pc[8];
#pragma unroll
  for (int i = 0; i < 8; ++i) pc[i] = __shfl_xor(c[i], 32);
  uint4 w1, w2;
  w1.x = hi ? pc[2] : c[0]; w1.y = hi ? pc[3] : c[1];
  w1.z = hi ? c[2] : pc[0]; w1.w = hi ? c[3] : pc[1];
  w2.x = hi ? pc[6] : c[4]; w2.y = hi ? pc[7] : c[5];
  w2.z = hi ? c[6] : pc[4]; w2.w = hi ? c[7] : pc[5];
  bf16x8 f1 = __builtin_bit_cast(bf16x8, w1);
  bf16x8 f2 = __builtin_bit_cast(bf16x8, w2);
  S.OTlo = __builtin_amdgcn_mfma_f32_32x32x16_bf16(v0, f1, S.OTlo, 0, 0, 0);
  S.OTlo = __builtin_amdgcn_mfma_f32_32x32x16_bf16(v1, f2, S.OTlo, 0, 0, 0);
  S.OThi = __builtin_amdgcn_mfma_f32_32x32x16_bf16(v2, f1, S.OThi, 0, 0, 0);
  S.OThi = __builtin_amdgcn_mfma_f32_32x32x16_bf16(v3, f2, S.OThi, 0, 0, 0);
}

// K LDS layout: 32 rows x 8 chunks(16B); slot(c,r) = c*32+r -> byte c*512 + r*16.
// V LDS layout: 64 rows x 4 chunks(16B); slot(c,r) = c*64+r -> byte c*1024 + r*16.
// Both staged via gload_lds linear dest; read at 16B/lane, 4 lanes/bank-group (optimal).
__global__ __launch_bounds__(256, 2) void k_attn(const unsigned short* __restrict__ qkv,
                                                 const unsigned short* __restrict__ vt,
                                                 unsigned short* __restrict__ y) {
  __shared__ __align__(16) unsigned short Ks[2][2048];
  __shared__ __align__(16) unsigned short Vs[2][2048];
  const int bh = blockIdx.x, b = bh >> 4, h = bh & 15;
  const int wv = threadIdx.x >> 6, lane = threadIdx.x & 63;
  const int by = blockIdx.y;
  const int w = by * 4 + wv;  // 0..31
  const int lq = lane & 31, hi = lane >> 5;
  const int ntL = w, ntH = 63 - w;
  const int q0L = w * 32, q0H = (63 - w) * 32;
  const int T = 64 - 4 * by;  // lockstep iterations; T-1 == max ntH in block

  // Q fragments (B-operand): lane j=lq reads Q row q0+lq, k=ki*16+hi*8+e
  const unsigned short* qrowL = qkv + ((size_t)(b * TSEQ) + q0L + lq) * (3 * CDIM) + h * HDIM;
  const unsigned short* qrowH = qkv + ((size_t)(b * TSEQ) + q0H + lq) * (3 * CDIM) + h * HDIM;
  bf16x8 qL0 = *(const bf16x8*)(qrowL + 0 + hi * 8);
  bf16x8 qL1 = *(const bf16x8*)(qrowL + 16 + hi * 8);
  bf16x8 qL2 = *(const bf16x8*)(qrowL + 32 + hi * 8);
  bf16x8 qL3 = *(const bf16x8*)(qrowL + 48 + hi * 8);
  bf16x8 qH0 = *(const bf16x8*)(qrowH + 0 + hi * 8);
  bf16x8 qH1 = *(const bf16x8*)(qrowH + 16 + hi * 8);
  bf16x8 qH2 = *(const bf16x8*)(qrowH + 32 + hi * 8);
  bf16x8 qH3 = *(const bf16x8*)(qrowH + 48 + hi * 8);

  // staging sources (per-lane global addr; LDS dest linear lane*16)
  // K: wave wv covers chunks {2wv, 2wv+1}: lane l -> row l&31, chunk wv*2+(l>>5)
  const int kr = lane & 31, kc = wv * 2 + (lane >> 5);
  const unsigned short* gK =
      qkv + ((size_t)(b * TSEQ) + kr) * (3 * CDIM) + CDIM + h * HDIM + kc * 8;
  // V: wave wv covers chunk wv: lane l -> row l (d), elems kv0 + wv*8
  const unsigned short* gV = vt + ((size_t)bh * HDIM + lane) * TSEQ + wv * 8;

#define STAGEKV(bf_, tt)                                                  \
  do {                                                                    \
    ldg_lds16((char*)Ks[bf_] + wv * 1024, gK + (size_t)(tt) * 32 * (3 * CDIM)); \
    ldg_lds16((char*)Vs[bf_] + wv * 1024, gV + (tt) * 32);                \
  } while (0)

  QSt SL, SH;
#pragma unroll
  for (int r = 0; r < 16; ++r) {
    SL.OTlo[r] = 0.f; SL.OThi[r] = 0.f; SH.OTlo[r] = 0.f; SH.OThi[r] = 0.f;
  }
  SL.m = -1e30f; SL.l = 0.f; SH.m = -1e30f; SH.l = 0.f;

  STAGEKV(0, 0);
  for (int t = 0; t < T; ++t) {
    __syncthreads();  // drains vmcnt (stage of buf[t&1]) + syncs reads of buf[(t+1)&1]
    if (t + 1 < T) STAGEKV((t + 1) & 1, t + 1);
    if (t <= ntH) {
      const unsigned short* Kb = Ks[t & 1];
      const unsigned short* Vb = Vs[t & 1];
      bf16x8 k0 = *(const bf16x8*)(Kb + (0 + hi) * 256 + lq * 8);
      bf16x8 k1 = *(const bf16x8*)(Kb + (2 + hi) * 256 + lq * 8);
      bf16x8 k2 = *(const bf16x8*)(Kb + (4 + hi) * 256 + lq * 8);
      bf16x8 k3 = *(const bf16x8*)(Kb + (6 + hi) * 256 + lq * 8);
      bf16x8 v0 = *(const bf16x8*)(Vb + hi * 512 + lq * 8);
      bf16x8 v1 = *(const bf16x8*)(Vb + (2 + hi) * 512 + lq * 8);
      bf16x8 v2 = *(const bf16x8*)(Vb + hi * 512 + (lq + 32) * 8);
      bf16x8 v3 = *(const bf16x8*)(Vb + (2 + hi) * 512 + (lq + 32) * 8);
      attn_qk_sm_pv(k0, k1, k2, k3, v0, v1, v2, v3,
                    qH0, qH1, qH2, qH3, SH, t == ntH, lq, hi);
      if (t <= ntL)
        attn_qk_sm_pv(k0, k1, k2, k3, v0, v1, v2, v3,
                      qL0, qL1, qL2, qL3, SL, t == ntL, lq, hi);
    }
  }
#undef STAGEKV

  {
    float inv = 1.f / SH.l;
    unsigned short* yrow = y + ((size_t)(b * TSEQ) + q0H + lq) * CDIM + h * HDIM;
#pragma unroll
    for (int r = 0; r < 16; r += 2) {
      int d = (r & 3) + 8 * (r >> 2) + 4 * hi;
      unsigned lo0 = f2bf(SH.OTlo[r] * inv), lo1 = f2bf(SH.OTlo[r + 1] * inv);
      *(unsigned*)(yrow + d) = lo0 | (lo1 << 16);
      unsigned h0 = f2bf(SH.OThi[r] * inv), h1 = f2bf(SH.OThi[r + 1] * inv);
      *(unsigned*)(yrow + 32 + d) = h0 | (h1 << 16);
    }
  }
  {
    float inv = 1.f / SL.l;
    unsigned short* yrow = y + ((size_t)(b * TSEQ) + q0L + lq) * CDIM + h * HDIM;
#pragma unroll
    for (int r = 0; r < 16; r += 2) {
      int d = (r & 3) + 8 * (r >> 2) + 4 * hi;
      unsigned lo0 = f2bf(SL.OTlo[r] * inv), lo1 = f2bf(SL.OTlo[r + 1] * inv);
      *(unsigned*)(yrow + d) = lo0 | (lo1 << 16);
      unsigned h0 = f2bf(SL.OThi[r] * inv), h1 = f2bf(SL.OThi[r + 1] * inv);
      *(unsigned*)(yrow + 32 + d) = h0 | (h1 << 16);
    }
  }
}

// ---------------- launch
extern "C" void kernel_launch(void* const* d_in, const int* in_sizes, int n_in,
                              void* d_out, int out_size, void* d_ws, size_t ws_size,
                              hipStream_t stream) {
  const float* x = (const float*)d_in[0];
  const float* ln1_w = (const float*)d_in[1];
  const float* ln1_b = (const float*)d_in[2];
  const float* attn_w = (const float*)d_in[3];
  const float* attn_b = (const float*)d_in[4];
  const float* proj_w = (const float*)d_in[5];
  const float* proj_b = (const float*)d_in[6];
  const float* ln2_w = (const float*)d_in[7];
  const float* ln2_b = (const float*)d_in[8];
  const float* fc_w = (const float*)d_in[9];
  const float* fc_b = (const float*)d_in[10];
  const float* fc_proj_w = (const float*)d_in[11];
  const float* fc_proj_b = (const float*)d_in[12];

  char* ws = (char*)d_ws;
  unsigned short* wt_attn = (unsigned short*)(ws + 0);           // [3072][1024] bf16
  unsigned short* wt_proj = (unsigned short*)(ws + 6291456);     // [1024][1024]
  unsigned short* wt_fc = (unsigned short*)(ws + 8388608);       // [4096][1024]
  unsigned short* wt_fcp = (unsigned short*)(ws + 16777216);     // [1024][4096]
  float* x1 = (float*)(ws + 25165824);                           // [8192][1024] fp32
  unsigned short* hbuf = (unsigned short*)(ws + 58720256);       // [8192][1024] bf16
  unsigned short* ybuf = (unsigned short*)(ws + 75497472);       // [8192][1024] bf16
  unsigned short* qkvb = (unsigned short*)(ws + 92274688);       // [8192][3072] bf16
  unsigned short* vtb = (unsigned short*)(ws + 142606336);       // [64][64][2048] bf16
  unsigned short* gbuf = (unsigned short*)(ws + 92274688);       // [8192][4096] bf16 (aliases qkv+vt)

  // 1. weight transposes
  k_wtrans<<<dim3(3072 / 32, 1024 / 32), 256, 0, stream>>>(attn_w, wt_attn, 1024, 3072);
  k_wtrans<<<dim3(1024 / 32, 1024 / 32), 256, 0, stream>>>(proj_w, wt_proj, 1024, 1024);
  k_wtrans<<<dim3(4096 / 32, 1024 / 32), 256, 0, stream>>>(fc_w, wt_fc, 1024, 4096);
  k_wtrans<<<dim3(1024 / 32, 4096 / 32), 256, 0, stream>>>(fc_proj_w, wt_fcp, 4096, 1024);

  // 2. LN1
  k_ln<<<NROWS, 256, 0, stream>>>(x, ln1_w, ln1_b, hbuf);

  // 3. qkv = h @ attn_w + attn_b
  k_gemm8<0><<<dim3(3072 / 256, NROWS / 128), 512, 0, stream>>>(
      hbuf, wt_attn, attn_b, nullptr, qkvb, NROWS, 3072, 1024);

  // 4. V^T
  k_build_vt<<<dim3(64, TSEQ / 64), 256, 0, stream>>>(qkvb, vtb);

  // 5. flash attention (block-shared LDS K/V staging)
  k_attn<<<dim3(64, 8), 256, 0, stream>>>(qkvb, vtb, ybuf);

  // 6. x1 = x + y @ proj_w + proj_b
  k_gemm8<2><<<dim3(1024 / 256, NROWS / 128), 512, 0, stream>>>(
      ybuf, wt_proj, proj_b, x, x1, NROWS, 1024, 1024);

  // 7. LN2
  k_ln<<<NROWS, 256, 0, stream>>>(x1, ln2_w, ln2_b, hbuf);

  // 8. g = gelu(h @ fc_w + fc_b)
  k_gemm8<1><<<dim3(4096 / 256, NROWS / 128), 512, 0, stream>>>(
      hbuf, wt_fc, fc_b, nullptr, gbuf, NROWS, 4096, 1024);

  // 9. out = x1 + g @ fc_proj_w + fc_proj_b
  k_gemm8<2><<<dim3(1024 / 256, NROWS / 128), 512, 0, stream>>>(
      gbuf, wt_fcp, fc_proj_b, x1, (float*)d_out, NROWS, 1024, 4096);
}

// Round 6
// 374.528 us; speedup vs baseline: 1.6827x; 1.0418x over previous
//
#include <hip/hip_runtime.h>
#include <stdint.h>

// Problem constants (B=4, T=2048, C=1024, H=16, HD=64)
#define TSEQ 2048
#define CDIM 1024
#define NHEAD 16
#define HDIM 64
#define NROWS 8192  // B*T

typedef __bf16 bf16x8 __attribute__((ext_vector_type(8)));
typedef float f32x4 __attribute__((ext_vector_type(4)));
typedef float f32x16 __attribute__((ext_vector_type(16)));

__device__ __forceinline__ unsigned short f2bf(float f) {
  unsigned u = __builtin_bit_cast(unsigned, f);
  u = u + 0x7fffu + ((u >> 16) & 1u);
  return (unsigned short)(u >> 16);
}

__device__ __forceinline__ unsigned cvt_pk_bf16(float a, float b) {
  unsigned r;
  asm("v_cvt_pk_bf16_f32 %0, %1, %2" : "=v"(r) : "v"(a), "v"(b));
  return r;
}

__device__ __forceinline__ float gelu_f(float x) {
  float x3 = x * x * x;
  float z = 0.7978845608028654f * (x + 0.044715f * x3);
  float e = __expf(2.f * z);
  float t = 1.f - 2.f / (e + 1.f);
  return 0.5f * x * (1.f + t);
}

// async 16B global->LDS (lds dest must be wave-uniform; HW adds lane*16)
__device__ __forceinline__ void ldg_lds16(void* lds, const void* gsrc) {
  __builtin_amdgcn_global_load_lds(
      (__attribute__((address_space(1))) unsigned int*)(uintptr_t)gsrc,
      (__attribute__((address_space(3))) unsigned int*)lds,
      16, 0, 0);
}

// ---------------- weight transpose+convert: W fp32 [K][N] -> Wt bf16 [N][K]
__global__ __launch_bounds__(256) void k_wtrans(const float* __restrict__ W,
                                                unsigned short* __restrict__ Wt,
                                                int K, int N) {
  __shared__ unsigned short tl[32][40];
  int n0 = blockIdx.x * 32, k0 = blockIdx.y * 32;
  int tid = threadIdx.x;
  int r = tid >> 3, c4 = (tid & 7) * 4;
  float4 v = *(const float4*)(W + (size_t)(k0 + r) * N + n0 + c4);
  ushort4 o;
  o.x = f2bf(v.x); o.y = f2bf(v.y); o.z = f2bf(v.z); o.w = f2bf(v.w);
  *(ushort4*)&tl[r][c4] = o;
  __syncthreads();
  int n = tid >> 3, k4 = (tid & 7) * 4;
  ushort4 w;
  w.x = tl[k4 + 0][n]; w.y = tl[k4 + 1][n]; w.z = tl[k4 + 2][n]; w.w = tl[k4 + 3][n];
  *(ushort4*)(Wt + (size_t)(n0 + n) * K + k0 + k4) = w;
}

// ---------------- layernorm: fp32 [rows][1024] -> bf16 [rows][1024]
__global__ __launch_bounds__(256) void k_ln(const float* __restrict__ x,
                                            const float* __restrict__ w,
                                            const float* __restrict__ b,
                                            unsigned short* __restrict__ out) {
  int row = blockIdx.x;
  int tid = threadIdx.x;
  const float* xr = x + (size_t)row * CDIM;
  float4 v = *(const float4*)(xr + tid * 4);
  float s = v.x + v.y + v.z + v.w;
  float s2 = v.x * v.x + v.y * v.y + v.z * v.z + v.w * v.w;
#pragma unroll
  for (int off = 32; off; off >>= 1) {
    s += __shfl_xor(s, off);
    s2 += __shfl_xor(s2, off);
  }
  __shared__ float rbuf[8];
  int wv = tid >> 6, lane = tid & 63;
  if (lane == 0) { rbuf[wv] = s; rbuf[4 + wv] = s2; }
  __syncthreads();
  float S1 = rbuf[0] + rbuf[1] + rbuf[2] + rbuf[3];
  float S2 = rbuf[4] + rbuf[5] + rbuf[6] + rbuf[7];
  float mean = S1 * (1.f / CDIM);
  float var = S2 * (1.f / CDIM) - mean * mean;
  float rstd = rsqrtf(var + 1e-5f);
  float4 wv4 = *(const float4*)(w + tid * 4);
  float4 bv4 = *(const float4*)(b + tid * 4);
  ushort4 o;
  o.x = f2bf((v.x - mean) * rstd * wv4.x + bv4.x);
  o.y = f2bf((v.y - mean) * rstd * wv4.y + bv4.y);
  o.z = f2bf((v.z - mean) * rstd * wv4.z + bv4.z);
  o.w = f2bf((v.w - mean) * rstd * wv4.w + bv4.w);
  *(ushort4*)(out + (size_t)row * CDIM + tid * 4) = o;
}

// ---------------- bf16 GEMM, pipelined: C[M,N] = A[M,K] @ Bt[N,K]^T (+epilogue)
// BM=128, BN=256, BK=64; 8 waves (2Mx4N), per-wave 64x64; ring-3 LDS (144KB);
// counted vmcnt(6), raw s_barrier, setprio MFMA clusters.
// LDS swizzle: within each 1024B block (8 rows x 8 16B-slots), data (row,slot)
// is stored at slot^(row&7). gload_lds dest is linear; the per-lane GLOBAL
// source carries the inverse permutation (same involution); ds_read applies it.
// 64-lane fragment read footprint = 256 dwords covering each bank exactly 8x.
// EPI 0: +bias -> bf16; EPI 1: gelu(+bias) -> bf16; EPI 2: +bias+resid -> fp32
template <int EPI>
__global__ __launch_bounds__(512, 2)
void k_gemm8(const unsigned short* __restrict__ A,
             const unsigned short* __restrict__ Bt,
             const float* __restrict__ bias,
             const float* __restrict__ resid,
             void* __restrict__ Cout,
             int M, int N, int K) {
  __shared__ __align__(16) unsigned short lds[3 * 24576];  // 3 x (A 16KB + B 32KB)
  const int tid = threadIdx.x;
  const int wid = tid >> 6, lane = tid & 63;
  const int wm = wid >> 2, wn = wid & 3;
  const int fr = lane & 15, fq = lane >> 4;

  // XCD-aware bijective swizzle (m204) of flat block id
  const int gx = gridDim.x;
  int flat = blockIdx.y * gx + blockIdx.x;
  {
    const int nwg = gx * gridDim.y;
    int q = nwg >> 3, r = nwg & 7;
    int xcd = flat & 7, idx = flat >> 3;
    flat = (xcd < r ? xcd * (q + 1) : r * (q + 1) + (xcd - r) * q) + idx;
  }
  const int bx = flat % gx, by = flat / gx;
  const long brow = (long)by * 128, bcol = (long)bx * 256;

  // staging: lane l carries row l>>3 of the 8-row chunk, col-slot (l&7)^(l>>3)
  const int lrow = lane >> 3;
  const int kby = (((lane & 7) ^ (lane >> 3)) << 4);  // swizzled byte-in-row
  const char* gA = (const char*)(A + ((size_t)(brow + wid * 16 + lrow)) * K) + kby;
  const char* gB = (const char*)(Bt + ((size_t)(bcol + wid * 32 + lrow)) * K) + kby;

  const int NT = K >> 6;

#define STAGE_A(i, t, bf_)                                              \
  ldg_lds16((char*)(lds + (bf_) * 24576) + (wid * 2 + (i)) * 1024,      \
            gA + ((size_t)(i) * 8 * K + (size_t)(t) * 64) * 2)
#define STAGE_B(j, t, bf_)                                              \
  ldg_lds16((char*)(lds + (bf_) * 24576 + 8192) + (wid * 4 + (j)) * 1024, \
            gB + ((size_t)(j) * 8 * K + (size_t)(t) * 64) * 2)

  // prologue: stage tiles 0 and 1 (6 loads each, in tile order)
  STAGE_A(0, 0, 0); STAGE_A(1, 0, 0);
  STAGE_B(0, 0, 0); STAGE_B(1, 0, 0); STAGE_B(2, 0, 0); STAGE_B(3, 0, 0);
  STAGE_A(0, 1, 1); STAGE_A(1, 1, 1);
  STAGE_B(0, 1, 1); STAGE_B(1, 1, 1); STAGE_B(2, 1, 1); STAGE_B(3, 1, 1);

  f32x4 acc[4][4];
  const f32x4 vzero = {0.f, 0.f, 0.f, 0.f};
#pragma unroll
  for (int m = 0; m < 4; ++m)
#pragma unroll
    for (int n = 0; n < 4; ++n) acc[m][n] = vzero;

  const int r7 = fr & 7;  // row-bit part of the LDS slot involution
  int buf = 0;
  for (int t = 0; t < NT; ++t) {
    if (t + 1 < NT) asm volatile("s_waitcnt vmcnt(6)" ::: "memory");
    else            asm volatile("s_waitcnt vmcnt(0)" ::: "memory");
    __builtin_amdgcn_s_barrier();
    __builtin_amdgcn_sched_barrier(0);
    const char* pA = (const char*)(lds + buf * 24576);
    const char* pB = pA + 16384;
    int nbuf = buf + 2; if (nbuf >= 3) nbuf -= 3;
    // ---- phase 0: stage 3, read B(all)+A(m=0,1), 16 MFMA
    if (t + 2 < NT) { STAGE_A(0, t + 2, nbuf); STAGE_A(1, t + 2, nbuf); STAGE_B(0, t + 2, nbuf); }
    bf16x8 bfrag[4][2];
#pragma unroll
    for (int n = 0; n < 4; ++n)
#pragma unroll
      for (int kh = 0; kh < 2; ++kh)
        bfrag[n][kh] = *(const bf16x8*)(pB + (wn * 64 + n * 16 + fr) * 128 +
                                        ((((kh << 2) + fq) ^ r7) << 4));
    bf16x8 af01[2][2];
#pragma unroll
    for (int m = 0; m < 2; ++m)
#pragma unroll
      for (int kh = 0; kh < 2; ++kh)
        af01[m][kh] = *(const bf16x8*)(pA + (wm * 64 + m * 16 + fr) * 128 +
                                       ((((kh << 2) + fq) ^ r7) << 4));
    __builtin_amdgcn_s_setprio(1);
#pragma unroll
    for (int m = 0; m < 2; ++m)
#pragma unroll
      for (int n = 0; n < 4; ++n)
#pragma unroll
        for (int kh = 0; kh < 2; ++kh)
          acc[m][n] = __builtin_amdgcn_mfma_f32_16x16x32_bf16(af01[m][kh], bfrag[n][kh], acc[m][n], 0, 0, 0);
    __builtin_amdgcn_s_setprio(0);
    // ---- phase 1: stage 3, read A(m=2,3), 16 MFMA
    __builtin_amdgcn_s_barrier();
    if (t + 2 < NT) { STAGE_B(1, t + 2, nbuf); STAGE_B(2, t + 2, nbuf); STAGE_B(3, t + 2, nbuf); }
    bf16x8 af23[2][2];
#pragma unroll
    for (int m = 0; m < 2; ++m)
#pragma unroll
      for (int kh = 0; kh < 2; ++kh)
        af23[m][kh] = *(const bf16x8*)(pA + (wm * 64 + (m + 2) * 16 + fr) * 128 +
                                       ((((kh << 2) + fq) ^ r7) << 4));
    __builtin_amdgcn_s_setprio(1);
#pragma unroll
    for (int m = 0; m < 2; ++m)
#pragma unroll
      for (int n = 0; n < 4; ++n)
#pragma unroll
        for (int kh = 0; kh < 2; ++kh)
          acc[m + 2][n] = __builtin_amdgcn_mfma_f32_16x16x32_bf16(af23[m][kh], bfrag[n][kh], acc[m + 2][n], 0, 0, 0);
    __builtin_amdgcn_s_setprio(0);
    buf = buf + 1; if (buf == 3) buf = 0;
  }
#undef STAGE_A
#undef STAGE_B

  // epilogue
#pragma unroll
  for (int m = 0; m < 4; ++m) {
    long row = brow + wm * 64 + m * 16 + fq * 4;
#pragma unroll
    for (int n = 0; n < 4; ++n) {
      long col = bcol + wn * 64 + n * 16 + fr;
      float bv = bias[col];
#pragma unroll
      for (int r = 0; r < 4; ++r) {
        float v = acc[m][n][r] + bv;
        long idx = (row + r) * (long)N + col;
        if (EPI == 0) {
          ((unsigned short*)Cout)[idx] = f2bf(v);
        } else if (EPI == 1) {
          ((unsigned short*)Cout)[idx] = f2bf(gelu_f(v));
        } else {
          ((float*)Cout)[idx] = v + resid[idx];
        }
      }
    }
  }
}

// ---------------- build V^T: qkv bf16 [8192][3072] (v at col 2048+h*64) -> vt [b,h,64,2048]
__global__ __launch_bounds__(256) void k_build_vt(const unsigned short* __restrict__ qkv,
                                                  unsigned short* __restrict__ vt) {
  __shared__ __align__(16) unsigned short tl[64][80];
  int bh = blockIdx.x, b = bh >> 4, h = bh & 15;
  int t0 = blockIdx.y * 64;
  int tid = threadIdx.x;
  int r = tid >> 2, cb = (tid & 3) * 16;
  const unsigned short* src =
      qkv + (size_t)(b * TSEQ + t0 + r) * (3 * CDIM) + 2 * CDIM + h * HDIM + cb;
  *(uint4*)&tl[r][cb] = *(const uint4*)src;
  *(uint4*)&tl[r][cb + 8] = *(const uint4*)(src + 8);
  __syncthreads();
  int d = tid >> 2, tb = (tid & 3) * 16;
  union { unsigned short u[16]; uint4 v[2]; } o;
#pragma unroll
  for (int j = 0; j < 16; ++j) o.u[j] = tl[tb + j][d];
  unsigned short* dst = vt + ((size_t)bh * HDIM + d) * TSEQ + t0 + tb;
  *(uint4*)dst = o.v[0];
  *(uint4*)(dst + 8) = o.v[1];
}

// ---------------- flash attention (causal), swapped-QK^T 32x32, paired q-tiles,
// block-shared LDS-staged K/V (chunk-column-major: bank-optimal, no swizzle needed).
struct QSt {
  f32x16 OTlo, OThi;
  float m, l;
};

__device__ __forceinline__ void attn_qk_sm_pv(
    const bf16x8& k0, const bf16x8& k1, const bf16x8& k2, const bf16x8& k3,
    const bf16x8& v0, const bf16x8& v1, const bf16x8& v2, const bf16x8& v3,
    const bf16x8& q0f, const bf16x8& q1f, const bf16x8& q2f, const bf16x8& q3f,
    QSt& S, bool diag, int lq, int hi) {
  const float SC = 0.125f * 1.44269504088896f;  // 1/sqrt(HD) * log2(e)
  f32x16 st;
#pragma unroll
  for (int r = 0; r < 16; ++r) st[r] = 0.f;
  st = __builtin_amdgcn_mfma_f32_32x32x16_bf16(k0, q0f, st, 0, 0, 0);
  st = __builtin_amdgcn_mfma_f32_32x32x16_bf16(k1, q1f, st, 0, 0, 0);
  st = __builtin_amdgcn_mfma_f32_32x32x16_bf16(k2, q2f, st, 0, 0, 0);
  st = __builtin_amdgcn_mfma_f32_32x32x16_bf16(k3, q3f, st, 0, 0, 0);
#pragma unroll
  for (int r = 0; r < 16; ++r) st[r] *= SC;
  if (diag) {
#pragma unroll
    for (int r = 0; r < 16; ++r) {
      int kvl = (r & 3) + 8 * (r >> 2) + 4 * hi;
      if (kvl > lq) st[r] = -1e30f;
    }
  }
  float tmax = st[0];
#pragma unroll
  for (int r = 1; r < 16; ++r) tmax = fmaxf(tmax, st[r]);
  float tm = fmaxf(tmax, __shfl_xor(tmax, 32));
  if (__any(tm > S.m + 8.f)) {  // T13 defer-max
    float mnew = fmaxf(S.m, tm);
    float alpha = __builtin_amdgcn_exp2f(S.m - mnew);
    S.m = mnew;
    S.OTlo *= alpha;
    S.OThi *= alpha;
    S.l *= alpha;
  }
  unsigned c[8];
  float rs = 0.f;
#pragma unroll
  for (int i = 0; i < 8; ++i) {
    float pa = __builtin_amdgcn_exp2f(st[2 * i] - S.m);
    float pb = __builtin_amdgcn_exp2f(st[2 * i + 1] - S.m);
    rs += pa + pb;
    c[i] = cvt_pk_bf16(pa, pb);
  }
  S.l += rs + __shfl_xor(rs, 32);
  unsigned pc[8];
#pragma unroll
  for (int i = 0; i < 8; ++i) pc[i] = __shfl_xor(c[i], 32);
  uint4 w1, w2;
  w1.x = hi ? pc[2] : c[0]; w1.y = hi ? pc[3] : c[1];
  w1.z = hi ? c[2] : pc[0]; w1.w = hi ? c[3] : pc[1];
  w2.x = hi ? pc[6] : c[4]; w2.y = hi ? pc[7] : c[5];
  w2.z = hi ? c[6] : pc[4]; w2.w = hi ? c[7] : pc[5];
  bf16x8 f1 = __builtin_bit_cast(bf16x8, w1);
  bf16x8 f2 = __builtin_bit_cast(bf16x8, w2);
  S.OTlo = __builtin_amdgcn_mfma_f32_32x32x16_bf16(v0, f1, S.OTlo, 0, 0, 0);
  S.OTlo = __builtin_amdgcn_mfma_f32_32x32x16_bf16(v1, f2, S.OTlo, 0, 0, 0);
  S.OThi = __builtin_amdgcn_mfma_f32_32x32x16_bf16(v2, f1, S.OThi, 0, 0, 0);
  S.OThi = __builtin_amdgcn_mfma_f32_32x32x16_bf16(v3, f2, S.OThi, 0, 0, 0);
}

// K LDS layout: 32 rows x 8 chunks(16B); slot(c,r) = c*32+r -> byte c*512 + r*16.
// V LDS layout: 64 rows x 4 chunks(16B); slot(c,r) = c*64+r -> byte c*1024 + r*16.
// Both staged via gload_lds linear dest; read at 16B/lane, consecutive lanes ->
// consecutive 16B units (bank-even footprint).
__global__ __launch_bounds__(256, 2) void k_attn(const unsigned short* __restrict__ qkv,
                                                 const unsigned short* __restrict__ vt,
                                                 unsigned short* __restrict__ y) {
  __shared__ __align__(16) unsigned short Ks[2][2048];
  __shared__ __align__(16) unsigned short Vs[2][2048];
  const int bh = blockIdx.x, b = bh >> 4, h = bh & 15;
  const int wv = threadIdx.x >> 6, lane = threadIdx.x & 63;
  const int by = blockIdx.y;
  const int w = by * 4 + wv;  // 0..31
  const int lq = lane & 31, hi = lane >> 5;
  const int ntL = w, ntH = 63 - w;
  const int q0L = w * 32, q0H = (63 - w) * 32;
  const int T = 64 - 4 * by;  // lockstep iterations; T-1 == max ntH in block

  // Q fragments (B-operand): lane j=lq reads Q row q0+lq, k=ki*16+hi*8+e
  const unsigned short* qrowL = qkv + ((size_t)(b * TSEQ) + q0L + lq) * (3 * CDIM) + h * HDIM;
  const unsigned short* qrowH = qkv + ((size_t)(b * TSEQ) + q0H + lq) * (3 * CDIM) + h * HDIM;
  bf16x8 qL0 = *(const bf16x8*)(qrowL + 0 + hi * 8);
  bf16x8 qL1 = *(const bf16x8*)(qrowL + 16 + hi * 8);
  bf16x8 qL2 = *(const bf16x8*)(qrowL + 32 + hi * 8);
  bf16x8 qL3 = *(const bf16x8*)(qrowL + 48 + hi * 8);
  bf16x8 qH0 = *(const bf16x8*)(qrowH + 0 + hi * 8);
  bf16x8 qH1 = *(const bf16x8*)(qrowH + 16 + hi * 8);
  bf16x8 qH2 = *(const bf16x8*)(qrowH + 32 + hi * 8);
  bf16x8 qH3 = *(const bf16x8*)(qrowH + 48 + hi * 8);

  // staging sources (per-lane global addr; LDS dest linear lane*16)
  const int kr = lane & 31, kc = wv * 2 + (lane >> 5);
  const unsigned short* gK =
      qkv + ((size_t)(b * TSEQ) + kr) * (3 * CDIM) + CDIM + h * HDIM + kc * 8;
  const unsigned short* gV = vt + ((size_t)bh * HDIM + lane) * TSEQ + wv * 8;

#define STAGEKV(bf_, tt)                                                  \
  do {                                                                    \
    ldg_lds16((char*)Ks[bf_] + wv * 1024, gK + (size_t)(tt) * 32 * (3 * CDIM)); \
    ldg_lds16((char*)Vs[bf_] + wv * 1024, gV + (tt) * 32);                \
  } while (0)

  QSt SL, SH;
#pragma unroll
  for (int r = 0; r < 16; ++r) {
    SL.OTlo[r] = 0.f; SL.OThi[r] = 0.f; SH.OTlo[r] = 0.f; SH.OThi[r] = 0.f;
  }
  SL.m = -1e30f; SL.l = 0.f; SH.m = -1e30f; SH.l = 0.f;

  STAGEKV(0, 0);
  for (int t = 0; t < T; ++t) {
    __syncthreads();  // drains vmcnt (stage of buf[t&1]) + syncs reads of buf[(t+1)&1]
    if (t + 1 < T) STAGEKV((t + 1) & 1, t + 1);
    if (t <= ntH) {
      const unsigned short* Kb = Ks[t & 1];
      const unsigned short* Vb = Vs[t & 1];
      bf16x8 k0 = *(const bf16x8*)(Kb + (0 + hi) * 256 + lq * 8);
      bf16x8 k1 = *(const bf16x8*)(Kb + (2 + hi) * 256 + lq * 8);
      bf16x8 k2 = *(const bf16x8*)(Kb + (4 + hi) * 256 + lq * 8);
      bf16x8 k3 = *(const bf16x8*)(Kb + (6 + hi) * 256 + lq * 8);
      bf16x8 v0 = *(const bf16x8*)(Vb + hi * 512 + lq * 8);
      bf16x8 v1 = *(const bf16x8*)(Vb + (2 + hi) * 512 + lq * 8);
      bf16x8 v2 = *(const bf16x8*)(Vb + hi * 512 + (lq + 32) * 8);
      bf16x8 v3 = *(const bf16x8*)(Vb + (2 + hi) * 512 + (lq + 32) * 8);
      attn_qk_sm_pv(k0, k1, k2, k3, v0, v1, v2, v3,
                    qH0, qH1, qH2, qH3, SH, t == ntH, lq, hi);
      if (t <= ntL)
        attn_qk_sm_pv(k0, k1, k2, k3, v0, v1, v2, v3,
                      qL0, qL1, qL2, qL3, SL, t == ntL, lq, hi);
    }
  }
#undef STAGEKV

  {
    float inv = 1.f / SH.l;
    unsigned short* yrow = y + ((size_t)(b * TSEQ) + q0H + lq) * CDIM + h * HDIM;
#pragma unroll
    for (int r = 0; r < 16; r += 2) {
      int d = (r & 3) + 8 * (r >> 2) + 4 * hi;
      unsigned lo0 = f2bf(SH.OTlo[r] * inv), lo1 = f2bf(SH.OTlo[r + 1] * inv);
      *(unsigned*)(yrow + d) = lo0 | (lo1 << 16);
      unsigned h0 = f2bf(SH.OThi[r] * inv), h1 = f2bf(SH.OThi[r + 1] * inv);
      *(unsigned*)(yrow + 32 + d) = h0 | (h1 << 16);
    }
  }
  {
    float inv = 1.f / SL.l;
    unsigned short* yrow = y + ((size_t)(b * TSEQ) + q0L + lq) * CDIM + h * HDIM;
#pragma unroll
    for (int r = 0; r < 16; r += 2) {
      int d = (r & 3) + 8 * (r >> 2) + 4 * hi;
      unsigned lo0 = f2bf(SL.OTlo[r] * inv), lo1 = f2bf(SL.OTlo[r + 1] * inv);
      *(unsigned*)(yrow + d) = lo0 | (lo1 << 16);
      unsigned h0 = f2bf(SL.OThi[r] * inv), h1 = f2bf(SL.OThi[r + 1] * inv);
      *(unsigned*)(yrow + 32 + d) = h0 | (h1 << 16);
    }
  }
}

// ---------------- launch
extern "C" void kernel_launch(void* const* d_in, const int* in_sizes, int n_in,
                              void* d_out, int out_size, void* d_ws, size_t ws_size,
                              hipStream_t stream) {
  const float* x = (const float*)d_in[0];
  const float* ln1_w = (const float*)d_in[1];
  const float* ln1_b = (const float*)d_in[2];
  const float* attn_w = (const float*)d_in[3];
  const float* attn_b = (const float*)d_in[4];
  const float* proj_w = (const float*)d_in[5];
  const float* proj_b = (const float*)d_in[6];
  const float* ln2_w = (const float*)d_in[7];
  const float* ln2_b = (const float*)d_in[8];
  const float* fc_w = (const float*)d_in[9];
  const float* fc_b = (const float*)d_in[10];
  const float* fc_proj_w = (const float*)d_in[11];
  const float* fc_proj_b = (const float*)d_in[12];

  char* ws = (char*)d_ws;
  unsigned short* wt_attn = (unsigned short*)(ws + 0);           // [3072][1024] bf16
  unsigned short* wt_proj = (unsigned short*)(ws + 6291456);     // [1024][1024]
  unsigned short* wt_fc = (unsigned short*)(ws + 8388608);       // [4096][1024]
  unsigned short* wt_fcp = (unsigned short*)(ws + 16777216);     // [1024][4096]
  float* x1 = (float*)(ws + 25165824);                           // [8192][1024] fp32
  unsigned short* hbuf = (unsigned short*)(ws + 58720256);       // [8192][1024] bf16
  unsigned short* ybuf = (unsigned short*)(ws + 75497472);       // [8192][1024] bf16
  unsigned short* qkvb = (unsigned short*)(ws + 92274688);       // [8192][3072] bf16
  unsigned short* vtb = (unsigned short*)(ws + 142606336);       // [64][64][2048] bf16
  unsigned short* gbuf = (unsigned short*)(ws + 92274688);       // [8192][4096] bf16 (aliases qkv+vt)

  // 1. weight transposes
  k_wtrans<<<dim3(3072 / 32, 1024 / 32), 256, 0, stream>>>(attn_w, wt_attn, 1024, 3072);
  k_wtrans<<<dim3(1024 / 32, 1024 / 32), 256, 0, stream>>>(proj_w, wt_proj, 1024, 1024);
  k_wtrans<<<dim3(4096 / 32, 1024 / 32), 256, 0, stream>>>(fc_w, wt_fc, 1024, 4096);
  k_wtrans<<<dim3(1024 / 32, 4096 / 32), 256, 0, stream>>>(fc_proj_w, wt_fcp, 4096, 1024);

  // 2. LN1
  k_ln<<<NROWS, 256, 0, stream>>>(x, ln1_w, ln1_b, hbuf);

  // 3. qkv = h @ attn_w + attn_b
  k_gemm8<0><<<dim3(3072 / 256, NROWS / 128), 512, 0, stream>>>(
      hbuf, wt_attn, attn_b, nullptr, qkvb, NROWS, 3072, 1024);

  // 4. V^T
  k_build_vt<<<dim3(64, TSEQ / 64), 256, 0, stream>>>(qkvb, vtb);

  // 5. flash attention (block-shared LDS K/V staging)
  k_attn<<<dim3(64, 8), 256, 0, stream>>>(qkvb, vtb, ybuf);

  // 6. x1 = x + y @ proj_w + proj_b
  k_gemm8<2><<<dim3(1024 / 256, NROWS / 128), 512, 0, stream>>>(
      ybuf, wt_proj, proj_b, x, x1, NROWS, 1024, 1024);

  // 7. LN2
  k_ln<<<NROWS, 256, 0, stream>>>(x1, ln2_w, ln2_b, hbuf);

  // 8. g = gelu(h @ fc_w + fc_b)
  k_gemm8<1><<<dim3(4096 / 256, NROWS / 128), 512, 0, stream>>>(
      hbuf, wt_fc, fc_b, nullptr, gbuf, NROWS, 4096, 1024);

  // 9. out = x1 + g @ fc_proj_w + fc_proj_b
  k_gemm8<2><<<dim3(1024 / 256, NROWS / 128), 512, 0, stream>>>(
      gbuf, wt_fcp, fc_proj_b, x1, (float*)d_out, NROWS, 1024, 4096);
}